// Round 5
// baseline (769.732 us; speedup 1.0000x reference)
//
#include <hip/hip_runtime.h>
#include <math.h>

#define DSZ 128
#define VOX (DSZ*DSZ*DSZ)  // 2,097,152 voxels
#define PD  130            // padded dim (halo 1 on all 6 faces)

typedef _Float16 half8 __attribute__((ext_vector_type(8)));
typedef _Float16 half4 __attribute__((ext_vector_type(4)));
typedef _Float16 half2v __attribute__((ext_vector_type(2)));
typedef float float4v __attribute__((ext_vector_type(4)));

// Halo-padded tensors: slot(z,y,x) = ((z+1)*130 + (y+1))*130 + (x+1),
// z,y,x in [-1,128]. 8-ch interleaved: halves = slot*8 (33.5 MiB).
// 1-ch: halves = slot (4.2 MiB). Halos zeroed once; interior-only writes.
// WB: interleaved [vox][28] halves (27 taps + 1 pad), 112 MiB.

// ---------------------------------------------------------------------------
// Zero the halo of a padded tensor (ws is re-poisoned before every call).
// ---------------------------------------------------------------------------
template<int CH>
__global__ __launch_bounds__(256) void zero_halo(_Float16* __restrict__ P)
{
    const int t = blockIdx.x * 256 + threadIdx.x;   // (zp,yp) row in [0,130)^2
    if (t >= PD * PD) return;
    const int zp = t / PD;
    const int yp = t - zp * PD;
    _Float16* row = P + (size_t)t * PD * CH;
    if (zp == 0 || zp == PD - 1 || yp == 0 || yp == PD - 1) {
        if (CH == 8) {
            half8 zz = {};
            for (int x = 0; x < PD; ++x) *(half8*)&row[x * 8] = zz;
        } else {
            for (int x = 0; x < PD; ++x) row[x] = (_Float16)0.0f;
        }
    } else {
        if (CH == 8) {
            half8 zz = {};
            *(half8*)&row[0] = zz;
            *(half8*)&row[(PD - 1) * 8] = zz;
        } else {
            row[0] = (_Float16)0.0f;
            row[PD - 1] = (_Float16)0.0f;
        }
    }
}

// ---------------------------------------------------------------------------
// Preformat conv weights -> fp16 [oc][tap(stride 29)][ic], once per launch.
// Blocks: 0..2 = ac{1,2,3}_w1; 3 = out_w; 4 = mid_w; 5..7 = ac{1,2,3}_w2.
// ---------------------------------------------------------------------------
__global__ __launch_bounds__(256) void preformat(const float* __restrict__ w1a, const float* __restrict__ w1b,
                                                 const float* __restrict__ w1c, const float* __restrict__ outw,
                                                 const float* __restrict__ midw,
                                                 const float* __restrict__ w2a, const float* __restrict__ w2b,
                                                 const float* __restrict__ w2c, _Float16* __restrict__ WF)
{
    const int bid = blockIdx.x, tid = threadIdx.x;
    const float* src;
    _Float16* dst;
    int nelem, sz;
    if (bid < 3)       { src = bid == 0 ? w1a : bid == 1 ? w1b : w1c; dst = WF + bid * 3712; nelem = 8 * 216; sz = 16 * 29; }
    else if (bid == 3) { src = outw; dst = WF + 3 * 3712; nelem = 216;     sz = 16 * 29; }
    else if (bid == 4) { src = midw; dst = WF + 4 * 3712; nelem = 8 * 216; sz = 16 * 29; }
    else               { src = bid == 5 ? w2a : bid == 6 ? w2b : w2c; dst = WF + 5 * 3712 + (bid - 5) * 7424; nelem = 27 * 216; sz = 32 * 29; }
    for (int i = tid; i < sz; i += 256) ((half8*)dst)[i] = half8{};
    __syncthreads();
    for (int i = tid; i < nelem; i += 256) {
        const int oc = i / 216;
        const int rem = i - oc * 216;
        const int ic = rem / 27;
        const int tap = rem - ic * 27;
        dst[(oc * 29 + tap) * 8 + ic] = (_Float16)src[i];
    }
}

// ---------------------------------------------------------------------------
// Cast planar fp32 (8ch) -> halo-padded interleaved fp16 (interior only).
// ---------------------------------------------------------------------------
__global__ __launch_bounds__(256) void cast_hp(const float* __restrict__ in,
                                               _Float16* __restrict__ hp)
{
    const int idx = blockIdx.x * 256 + threadIdx.x;
    const int w = idx & 127;
    const int h = (idx >> 7) & 127;
    const int d = idx >> 14;
    half8 v;
    #pragma unroll
    for (int ic = 0; ic < 8; ++ic) v[ic] = (_Float16)in[(size_t)ic * VOX + idx];
    const int slot = ((d + 1) * PD + (h + 1)) * PD + (w + 1);
    *(half8*)&hp[(size_t)slot * 8] = v;
}

// ---------------------------------------------------------------------------
// Dense 3x3x3 conv 8->8 (+bias, opt relu) via MFMA; padded in/out, ROWS=4.
// Grid 4096: b decodes to (d, h0) with h0 in steps of 4.
// ---------------------------------------------------------------------------
template<bool RELU>
__global__ __launch_bounds__(256) void conv8x8_mfma(const _Float16* __restrict__ DP,
                                                    const _Float16* __restrict__ WF,
                                                    const float* __restrict__ bias,
                                                    _Float16* __restrict__ HO)
{
    __shared__ _Float16 Wr[16 * 29 * 8];
    const int tid = threadIdx.x;
    for (int i = tid; i < 16 * 29; i += 256) ((half8*)Wr)[i] = ((const half8*)WF)[i];
    __syncthreads();

    const int b = ((blockIdx.x & 7) << 9) | (blockIdx.x >> 3);  // 4096 blocks
    const int h0 = (b & 31) << 2;
    const int d  = b >> 5;
    const int lane = tid & 63;
    const int wv   = tid >> 6;
    const int col  = lane & 15;
    const int q    = lane >> 4;

    half8 af[7];
    #pragma unroll
    for (int c = 0; c < 7; ++c)
        af[c] = *(const half8*)&Wr[(col * 29 + (c * 4 + q)) * 8];

    const int base0 = ((d + 1) * PD + (h0 + 1)) * PD + 1 + wv * 32 + col;
    const _Float16* p[7];
    #pragma unroll
    for (int c = 0; c < 7; ++c) {
        const int tap = min(c * 4 + q, 26);
        const int dz = tap / 9, r9 = tap - dz * 9;
        const int dy = r9 / 3,  dx = r9 - dy * 3;
        p[c] = DP + (size_t)(base0 + ((dz - 1) * PD + (dy - 1)) * PD + (dx - 1)) * 8;
    }

    #pragma unroll
    for (int r = 0; r < 4; ++r) {
        #pragma unroll
        for (int t2 = 0; t2 < 2; ++t2) {
            float4v acc = {0.0f, 0.0f, 0.0f, 0.0f};
            #pragma unroll
            for (int c = 0; c < 7; ++c) {
                const half8 bv = *(const half8*)(p[c] + (r * PD + t2 * 16) * 8);
                acc = __builtin_amdgcn_mfma_f32_16x16x32_f16(af[c], bv, acc, 0, 0, 0);
            }
            if (q < 2) {
                const float4v bl = ((const float4v*)bias)[q];
                half4 hv;
                #pragma unroll
                for (int rr = 0; rr < 4; ++rr) {
                    float v = acc[rr] + bl[rr];
                    if (RELU) v = fmaxf(v, 0.0f);
                    hv[rr] = (_Float16)v;
                }
                *(half4*)&HO[(size_t)(base0 + r * PD + t2 * 16) * 8 + q * 4] = hv;
            }
        }
    }
}

// ---------------------------------------------------------------------------
// Dense 3x3x3 conv 8->1 (+bias) via MFMA; padded in -> padded 1-ch fp16 out.
// ---------------------------------------------------------------------------
__global__ __launch_bounds__(256) void conv8x1_mfma(const _Float16* __restrict__ DP,
                                                    const _Float16* __restrict__ WF,
                                                    const float* __restrict__ bias,
                                                    _Float16* __restrict__ F)
{
    __shared__ _Float16 Wr[16 * 29 * 8];
    const int tid = threadIdx.x;
    for (int i = tid; i < 16 * 29; i += 256) ((half8*)Wr)[i] = ((const half8*)WF)[i];
    __syncthreads();

    const int b = ((blockIdx.x & 7) << 10) | (blockIdx.x >> 3);  // 8192 blocks
    const int h0 = (b & 63) << 1;
    const int d  = b >> 6;
    const int lane = tid & 63;
    const int wv   = tid >> 6;
    const int col  = lane & 15;
    const int q    = lane >> 4;

    half8 af[7];
    #pragma unroll
    for (int c = 0; c < 7; ++c)
        af[c] = *(const half8*)&Wr[(col * 29 + (c * 4 + q)) * 8];

    const int base0 = ((d + 1) * PD + (h0 + 1)) * PD + 1 + wv * 32 + col;
    const _Float16* p[7];
    #pragma unroll
    for (int c = 0; c < 7; ++c) {
        const int tap = min(c * 4 + q, 26);
        const int dz = tap / 9, r9 = tap - dz * 9;
        const int dy = r9 / 3,  dx = r9 - dy * 3;
        p[c] = DP + (size_t)(base0 + ((dz - 1) * PD + (dy - 1)) * PD + (dx - 1)) * 8;
    }

    const float b0 = bias[0];
    #pragma unroll
    for (int r = 0; r < 2; ++r) {
        #pragma unroll
        for (int t2 = 0; t2 < 2; ++t2) {
            float4v acc = {0.0f, 0.0f, 0.0f, 0.0f};
            #pragma unroll
            for (int c = 0; c < 7; ++c) {
                const half8 bv = *(const half8*)(p[c] + (r * PD + t2 * 16) * 8);
                acc = __builtin_amdgcn_mfma_f32_16x16x32_f16(af[c], bv, acc, 0, 0, 0);
            }
            if (q == 0)
                F[base0 + r * PD + t2 * 16] = (_Float16)(acc[0] + b0);
        }
    }
}

// ---------------------------------------------------------------------------
// 8 -> 27 conv + L1 normalize via MFMA; padded in, WB out [vox][28]. ROWS=4.
// q==3 hi half4 covers taps 28..31 — all pad, store skipped.
// ---------------------------------------------------------------------------
__global__ __launch_bounds__(256) void conv8x27n_mfma(const _Float16* __restrict__ HP,
                                                      const _Float16* __restrict__ WF,
                                                      _Float16* __restrict__ WB)
{
    __shared__ _Float16 Wr[32 * 29 * 8];
    const int tid = threadIdx.x;
    for (int i = tid; i < 32 * 29; i += 256) ((half8*)Wr)[i] = ((const half8*)WF)[i];
    __syncthreads();

    const int b = ((blockIdx.x & 7) << 9) | (blockIdx.x >> 3);  // 4096 blocks
    const int h0 = (b & 31) << 2;
    const int d  = b >> 5;
    const int lane = tid & 63;
    const int wv   = tid >> 6;
    const int col  = lane & 15;
    const int q    = lane >> 4;

    half8 af[2][7];
    #pragma unroll
    for (int t = 0; t < 2; ++t)
        #pragma unroll
        for (int c = 0; c < 7; ++c)
            af[t][c] = *(const half8*)&Wr[((t * 16 + col) * 29 + (c * 4 + q)) * 8];

    const int base0 = ((d + 1) * PD + (h0 + 1)) * PD + 1 + wv * 32 + col;
    const _Float16* p[7];
    #pragma unroll
    for (int c = 0; c < 7; ++c) {
        const int tap = min(c * 4 + q, 26);
        const int dz = tap / 9, r9 = tap - dz * 9;
        const int dy = r9 / 3,  dx = r9 - dy * 3;
        p[c] = HP + (size_t)(base0 + ((dz - 1) * PD + (dy - 1)) * PD + (dx - 1)) * 8;
    }

    #pragma unroll
    for (int r = 0; r < 4; ++r) {
        #pragma unroll
        for (int t2 = 0; t2 < 2; ++t2) {
            float4v acc0 = {0.0f, 0.0f, 0.0f, 0.0f};
            float4v acc1 = {0.0f, 0.0f, 0.0f, 0.0f};
            #pragma unroll
            for (int c = 0; c < 7; ++c) {
                const half8 bv = *(const half8*)(p[c] + (r * PD + t2 * 16) * 8);
                acc0 = __builtin_amdgcn_mfma_f32_16x16x32_f16(af[0][c], bv, acc0, 0, 0, 0);
                acc1 = __builtin_amdgcn_mfma_f32_16x16x32_f16(af[1][c], bv, acc1, 0, 0, 0);
            }

            float s = 0.0f;
            #pragma unroll
            for (int rr = 0; rr < 4; ++rr) {
                s += fabsf(acc0[rr]);
                if (16 + q * 4 + rr < 27) s += fabsf(acc1[rr]);
            }
            s += __shfl_xor(s, 16);
            s += __shfl_xor(s, 32);
            const float rcp = 1.0f / fmaxf(s, 1e-12f);

            const int vox = (d << 14) + ((h0 + r) << 7) + wv * 32 + t2 * 16 + col;
            const size_t base = (size_t)vox * 28;
            half4 o0, o1;
            #pragma unroll
            for (int rr = 0; rr < 4; ++rr) {
                o0[rr] = (_Float16)(acc0[rr] * rcp);
                o1[rr] = (_Float16)(acc1[rr] * rcp);   // pad rows produce 0
            }
            *(half4*)&WB[base + q * 4] = o0;
            if (q < 3)
                *(half4*)&WB[base + 16 + q * 4] = o1;  // q==3: taps 28..31, all pad
        }
    }
}

// ---------------------------------------------------------------------------
// Adaptive stencil, 8ch padded interleaved in/out; LDS-tiled input.
// Block = 2 y-rows x 128 x of one z-slice. Stage 3z x 4y x 130x halo tile
// (24,960 B) once; 27 taps read via conflict-free ds_read_b128.
// W loads hoisted above staging so their latency hides under it.
// Per-voxel accumulation order identical (dz,dy,kw) — bit-exact.
// ---------------------------------------------------------------------------
__global__ __launch_bounds__(256) void aconv8i(const _Float16* __restrict__ in,
                                               const _Float16* __restrict__ wb,
                                               _Float16* __restrict__ out)
{
    __shared__ _Float16 T[12 * 130 * 8];     // [dz(3)][yy(4)][xslot(130)][ch(8)]
    const int b = ((blockIdx.x & 7) << 10) | (blockIdx.x >> 3);  // 8192 blocks
    const int h0 = (b & 63) << 1;
    const int d  = b >> 6;
    const int tid = threadIdx.x;

    // hoisted per-voxel weight loads (latency hides under staging + barrier)
    const int idx = b * 256 + tid;
    const size_t wbb = (size_t)idx * 28;
    half4 W[7];
    #pragma unroll
    for (int k = 0; k < 7; ++k) W[k] = *(const half4*)(wb + wbb + k * 4);

    // stage: rows (d+dz, h0+yy) padded, full x range [0,130)
    for (int i = tid; i < 12 * 130; i += 256) {
        const int dz  = i / 520;
        const int rem = i - dz * 520;
        const int yy  = rem / 130;
        const int xs  = rem - yy * 130;
        ((half8*)T)[i] =
            *(const half8*)&in[((size_t)((d + dz) * PD + (h0 + yy)) * PD + xs) * 8];
    }
    __syncthreads();

    const int x  = tid & 127;
    const int ly = tid >> 7;                  // 0/1: which of the 2 y-rows

    half2v a4[4];
    #pragma unroll
    for (int j = 0; j < 4; ++j) a4[j] = half2v{};

    #pragma unroll
    for (int dz = 0; dz < 3; dz++) {
        #pragma unroll
        for (int dy = 0; dy < 3; dy++) {
            const _Float16* rp = &T[((dz * 4 + (ly + dy)) * 130 + (x + 1)) * 8];
            #pragma unroll
            for (int kw = 0; kw < 3; kw++) {
                const int tap = dz * 9 + dy * 3 + kw;
                const _Float16 wt = W[tap >> 2][tap & 3];
                half2v w2; w2[0] = wt; w2[1] = wt;
                const half8 hv = *(const half8*)(rp + (kw - 1) * 8);
                const half2v* h2 = (const half2v*)&hv;
                #pragma unroll
                for (int j = 0; j < 4; ++j)
                    a4[j] += h2[j] * w2;                 // v_pk_fma_f16
            }
        }
    }

    const int s0 = ((d + 1) * PD + (h0 + ly + 1)) * PD + (x + 1);
    half8 o;
    #pragma unroll
    for (int j = 0; j < 4; ++j) { o[2 * j] = a4[j][0]; o[2 * j + 1] = a4[j][1]; }
    *(half8*)&out[(size_t)s0 * 8] = o;
}

// ---------------------------------------------------------------------------
// Adaptive stencil, 1ch padded fp16 in; fp32 math; LDS-tiled input (3.1 KB).
// TANH=false: padded fp16 out. TANH=true: planar fp32 out (final).
// ---------------------------------------------------------------------------
template<bool TANH>
__global__ __launch_bounds__(256) void aconv1h(const _Float16* __restrict__ in,
                                               const _Float16* __restrict__ wb,
                                               _Float16* __restrict__ outh,
                                               float* __restrict__ outf)
{
    __shared__ _Float16 T[12 * 130];          // [dz(3)][yy(4)][xslot(130)]
    const int b = ((blockIdx.x & 7) << 10) | (blockIdx.x >> 3);  // 8192 blocks
    const int h0 = (b & 63) << 1;
    const int d  = b >> 6;
    const int tid = threadIdx.x;

    const int idx = b * 256 + tid;
    const size_t wbb = (size_t)idx * 28;
    half4 W[7];
    #pragma unroll
    for (int k = 0; k < 7; ++k) W[k] = *(const half4*)(wb + wbb + k * 4);

    for (int i = tid; i < 12 * 130; i += 256) {
        const int dz  = i / 520;
        const int rem = i - dz * 520;
        const int yy  = rem / 130;
        const int xs  = rem - yy * 130;
        T[i] = in[(size_t)((d + dz) * PD + (h0 + yy)) * PD + xs];
    }
    __syncthreads();

    const int x  = tid & 127;
    const int ly = tid >> 7;

    float acc = 0.0f;
    #pragma unroll
    for (int dz = 0; dz < 3; dz++) {
        #pragma unroll
        for (int dy = 0; dy < 3; dy++) {
            const _Float16* rp = &T[(dz * 4 + (ly + dy)) * 130 + (x + 1)];
            #pragma unroll
            for (int kw = 0; kw < 3; kw++) {
                const int tap = dz * 9 + dy * 3 + kw;
                const _Float16 wt = W[tap >> 2][tap & 3];
                acc = fmaf((float)rp[kw - 1], (float)wt, acc);
            }
        }
    }

    if (TANH) {
        outf[idx] = tanhf(acc);
    } else {
        const int s0 = ((d + 1) * PD + (h0 + ly + 1)) * PD + (x + 1);
        outh[s0] = (_Float16)acc;
    }
}

// ---------------------------------------------------------------------------
// ws layout (~192 MiB): P0 | P1 (33.5 MiB padded 8-ch each) | WB (112 MiB)
//   | F1 | G1 | F2 (4.2 MiB padded 1-ch each) | WF (preformatted weights).
// WF halves: [0]=ac1_w1 [3712]=ac2_w1 [7424]=ac3_w1 [11136]=out_w
//   [14848]=mid_w [18560]=ac1_w2 [25984]=ac2_w2 [33408]=ac3_w2
// ---------------------------------------------------------------------------
extern "C" void kernel_launch(void* const* d_in, const int* in_sizes, int n_in,
                              void* d_out, int out_size, void* d_ws, size_t ws_size,
                              hipStream_t stream)
{
    const float* x      = (const float*)d_in[0];
    const float* ac1_w1 = (const float*)d_in[1];
    const float* ac1_b1 = (const float*)d_in[2];
    const float* ac1_w2 = (const float*)d_in[3];
    const float* ac2_w1 = (const float*)d_in[4];
    const float* ac2_b1 = (const float*)d_in[5];
    const float* ac2_w2 = (const float*)d_in[6];
    const float* ac3_w1 = (const float*)d_in[7];
    const float* ac3_b1 = (const float*)d_in[8];
    const float* ac3_w2 = (const float*)d_in[9];
    const float* mid_w  = (const float*)d_in[10];
    const float* mid_b  = (const float*)d_in[11];
    const float* out_w  = (const float*)d_in[12];
    const float* out_b  = (const float*)d_in[13];
    float* out = (float*)d_out;

    char* ws = (char*)d_ws;
    const size_t PS8 = (size_t)PD * PD * PD * 8 * 2;   // 35,152,000 B
    const size_t PS1 = (size_t)PD * PD * PD * 2;       //  4,394,000 B
    const size_t WBsz = (size_t)VOX * 28 * 2;          // 117,440,512 B
    _Float16* P0 = (_Float16*)(ws);
    _Float16* P1 = (_Float16*)(ws + PS8);
    _Float16* WB = (_Float16*)(ws + 2 * PS8);
    _Float16* F1 = (_Float16*)(ws + 2 * PS8 + WBsz);
    _Float16* G1 = (_Float16*)(ws + 2 * PS8 + WBsz + PS1);
    _Float16* F2 = (_Float16*)(ws + 2 * PS8 + WBsz + 2 * PS1);
    _Float16* WF = (_Float16*)(ws + 2 * PS8 + WBsz + 3 * PS1);
    _Float16* WF8_1  = WF;
    _Float16* WF8_2  = WF + 3712;
    _Float16* WF8_3  = WF + 7424;
    _Float16* WFo    = WF + 11136;
    _Float16* WFmid  = WF + 14848;
    _Float16* WF27_1 = WF + 18560;
    _Float16* WF27_2 = WF + 25984;
    _Float16* WF27_3 = WF + 33408;

    const dim3 blk(256);
    const dim3 gridT(VOX / 256);               // cast, aconv: 8192 blocks
    const dim3 gridM4(VOX / 512);              // ROWS=4 MFMA convs: 4096 blocks
    const dim3 gridM2(VOX / 256);              // conv8x1 (ROWS=2): 8192 blocks
    const dim3 gridZ((PD * PD + 255) / 256);   // zero_halo: 67 blocks

    zero_halo<8><<<gridZ, blk, 0, stream>>>(P0);
    zero_halo<8><<<gridZ, blk, 0, stream>>>(P1);
    zero_halo<1><<<gridZ, blk, 0, stream>>>(F1);
    zero_halo<1><<<gridZ, blk, 0, stream>>>(G1);
    zero_halo<1><<<gridZ, blk, 0, stream>>>(F2);
    preformat<<<dim3(8), blk, 0, stream>>>(ac1_w1, ac2_w1, ac3_w1, out_w, mid_w,
                                           ac1_w2, ac2_w2, ac3_w2, WF);

    // ---- block 1 ----
    cast_hp<<<gridT, blk, 0, stream>>>(x, P0);                       // X16 = P0
    conv8x8_mfma<true ><<<gridM4, blk, 0, stream>>>(P0, WF8_1, ac1_b1, P1);  // H1
    conv8x27n_mfma<<<gridM4, blk, 0, stream>>>(P1, WF27_1, WB);
    aconv8i<<<gridT, blk, 0, stream>>>(P0, WB, P1);                  // (H1 dead)
    aconv8i<<<gridT, blk, 0, stream>>>(P1, WB, P0);
    aconv8i<<<gridT, blk, 0, stream>>>(P0, WB, P1);                  // C1 = P1
    // ---- mid conv ----
    conv8x8_mfma<false><<<gridM4, blk, 0, stream>>>(P1, WFmid, mid_b, P0);   // M = P0
    // ---- block 2 ----
    conv8x8_mfma<true ><<<gridM4, blk, 0, stream>>>(P0, WF8_2, ac2_b1, P1);  // H2
    conv8x27n_mfma<<<gridM4, blk, 0, stream>>>(P1, WF27_2, WB);
    aconv8i<<<gridT, blk, 0, stream>>>(P0, WB, P1);
    aconv8i<<<gridT, blk, 0, stream>>>(P1, WB, P0);
    aconv8i<<<gridT, blk, 0, stream>>>(P0, WB, P1);                  // mid2 = P1
    // ---- block 3 (weights from mid2 = P1) ----
    conv8x8_mfma<true ><<<gridM4, blk, 0, stream>>>(P1, WF8_3, ac3_b1, P0);  // H3
    conv8x27n_mfma<<<gridM4, blk, 0, stream>>>(P0, WF27_3, WB);
    conv8x1_mfma<<<gridM2, blk, 0, stream>>>(P1, WFo, out_b, F1);
    aconv1h<false><<<gridT, blk, 0, stream>>>(F1, WB, G1, nullptr);
    aconv1h<false><<<gridT, blk, 0, stream>>>(G1, WB, F2, nullptr);
    aconv1h<true ><<<gridT, blk, 0, stream>>>(F2, WB, nullptr, out);
}

// Round 6
// 741.261 us; speedup vs baseline: 1.0384x; 1.0384x over previous
//
#include <hip/hip_runtime.h>
#include <math.h>

#define DSZ 128
#define VOX (DSZ*DSZ*DSZ)  // 2,097,152 voxels
#define PD  130            // padded dim (halo 1 on all 6 faces)

typedef _Float16 half8 __attribute__((ext_vector_type(8)));
typedef _Float16 half4 __attribute__((ext_vector_type(4)));
typedef _Float16 half2v __attribute__((ext_vector_type(2)));
typedef float float4v __attribute__((ext_vector_type(4)));

// Halo-padded tensors: slot(z,y,x) = ((z+1)*130 + (y+1))*130 + (x+1),
// z,y,x in [-1,128]. 8-ch interleaved: halves = slot*8 (33.5 MiB).
// 1-ch: halves = slot (4.2 MiB). Halos zeroed once; interior-only writes.
// WB: interleaved [vox][28] halves (27 taps + 1 pad), 112 MiB.

// ---------------------------------------------------------------------------
// Zero the halo of a padded tensor (ws is re-poisoned before every call).
// ---------------------------------------------------------------------------
template<int CH>
__global__ __launch_bounds__(256) void zero_halo(_Float16* __restrict__ P)
{
    const int t = blockIdx.x * 256 + threadIdx.x;   // (zp,yp) row in [0,130)^2
    if (t >= PD * PD) return;
    const int zp = t / PD;
    const int yp = t - zp * PD;
    _Float16* row = P + (size_t)t * PD * CH;
    if (zp == 0 || zp == PD - 1 || yp == 0 || yp == PD - 1) {
        if (CH == 8) {
            half8 zz = {};
            for (int x = 0; x < PD; ++x) *(half8*)&row[x * 8] = zz;
        } else {
            for (int x = 0; x < PD; ++x) row[x] = (_Float16)0.0f;
        }
    } else {
        if (CH == 8) {
            half8 zz = {};
            *(half8*)&row[0] = zz;
            *(half8*)&row[(PD - 1) * 8] = zz;
        } else {
            row[0] = (_Float16)0.0f;
            row[PD - 1] = (_Float16)0.0f;
        }
    }
}

// ---------------------------------------------------------------------------
// Preformat conv weights -> fp16 [oc][tap(stride 29)][ic], once per launch.
// Blocks: 0..2 = ac{1,2,3}_w1; 3 = out_w; 4 = mid_w; 5..7 = ac{1,2,3}_w2.
// ---------------------------------------------------------------------------
__global__ __launch_bounds__(256) void preformat(const float* __restrict__ w1a, const float* __restrict__ w1b,
                                                 const float* __restrict__ w1c, const float* __restrict__ outw,
                                                 const float* __restrict__ midw,
                                                 const float* __restrict__ w2a, const float* __restrict__ w2b,
                                                 const float* __restrict__ w2c, _Float16* __restrict__ WF)
{
    const int bid = blockIdx.x, tid = threadIdx.x;
    const float* src;
    _Float16* dst;
    int nelem, sz;
    if (bid < 3)       { src = bid == 0 ? w1a : bid == 1 ? w1b : w1c; dst = WF + bid * 3712; nelem = 8 * 216; sz = 16 * 29; }
    else if (bid == 3) { src = outw; dst = WF + 3 * 3712; nelem = 216;     sz = 16 * 29; }
    else if (bid == 4) { src = midw; dst = WF + 4 * 3712; nelem = 8 * 216; sz = 16 * 29; }
    else               { src = bid == 5 ? w2a : bid == 6 ? w2b : w2c; dst = WF + 5 * 3712 + (bid - 5) * 7424; nelem = 27 * 216; sz = 32 * 29; }
    for (int i = tid; i < sz; i += 256) ((half8*)dst)[i] = half8{};
    __syncthreads();
    for (int i = tid; i < nelem; i += 256) {
        const int oc = i / 216;
        const int rem = i - oc * 216;
        const int ic = rem / 27;
        const int tap = rem - ic * 27;
        dst[(oc * 29 + tap) * 8 + ic] = (_Float16)src[i];
    }
}

// ---------------------------------------------------------------------------
// Cast planar fp32 (8ch) -> halo-padded interleaved fp16 (interior only).
// ---------------------------------------------------------------------------
__global__ __launch_bounds__(256) void cast_hp(const float* __restrict__ in,
                                               _Float16* __restrict__ hp)
{
    const int idx = blockIdx.x * 256 + threadIdx.x;
    const int w = idx & 127;
    const int h = (idx >> 7) & 127;
    const int d = idx >> 14;
    half8 v;
    #pragma unroll
    for (int ic = 0; ic < 8; ++ic) v[ic] = (_Float16)in[(size_t)ic * VOX + idx];
    const int slot = ((d + 1) * PD + (h + 1)) * PD + (w + 1);
    *(half8*)&hp[(size_t)slot * 8] = v;
}

// ---------------------------------------------------------------------------
// Dense 3x3x3 conv 8->8 (+bias, opt relu) via MFMA; padded in/out, ROWS=2.
// (R3-verified form.)
// ---------------------------------------------------------------------------
template<bool RELU>
__global__ __launch_bounds__(256) void conv8x8_mfma(const _Float16* __restrict__ DP,
                                                    const _Float16* __restrict__ WF,
                                                    const float* __restrict__ bias,
                                                    _Float16* __restrict__ HO)
{
    __shared__ _Float16 Wr[16 * 29 * 8];
    const int tid = threadIdx.x;
    for (int i = tid; i < 16 * 29; i += 256) ((half8*)Wr)[i] = ((const half8*)WF)[i];
    __syncthreads();

    const int b = ((blockIdx.x & 7) << 10) | (blockIdx.x >> 3);  // 8192 blocks
    const int h0 = (b & 63) << 1;
    const int d  = b >> 6;
    const int lane = tid & 63;
    const int wv   = tid >> 6;
    const int col  = lane & 15;
    const int q    = lane >> 4;

    half8 af[7];
    #pragma unroll
    for (int c = 0; c < 7; ++c)
        af[c] = *(const half8*)&Wr[(col * 29 + (c * 4 + q)) * 8];

    const int base0 = ((d + 1) * PD + (h0 + 1)) * PD + 1 + wv * 32 + col;
    const _Float16* p[7];
    #pragma unroll
    for (int c = 0; c < 7; ++c) {
        const int tap = min(c * 4 + q, 26);
        const int dz = tap / 9, r9 = tap - dz * 9;
        const int dy = r9 / 3,  dx = r9 - dy * 3;
        p[c] = DP + (size_t)(base0 + ((dz - 1) * PD + (dy - 1)) * PD + (dx - 1)) * 8;
    }

    #pragma unroll
    for (int r = 0; r < 2; ++r) {
        #pragma unroll
        for (int t2 = 0; t2 < 2; ++t2) {
            float4v acc = {0.0f, 0.0f, 0.0f, 0.0f};
            #pragma unroll
            for (int c = 0; c < 7; ++c) {
                const half8 bv = *(const half8*)(p[c] + (r * PD + t2 * 16) * 8);
                acc = __builtin_amdgcn_mfma_f32_16x16x32_f16(af[c], bv, acc, 0, 0, 0);
            }
            if (q < 2) {
                const float4v bl = ((const float4v*)bias)[q];
                half4 hv;
                #pragma unroll
                for (int rr = 0; rr < 4; ++rr) {
                    float v = acc[rr] + bl[rr];
                    if (RELU) v = fmaxf(v, 0.0f);
                    hv[rr] = (_Float16)v;
                }
                *(half4*)&HO[(size_t)(base0 + r * PD + t2 * 16) * 8 + q * 4] = hv;
            }
        }
    }
}

// ---------------------------------------------------------------------------
// Dense 3x3x3 conv 8->1 (+bias) via MFMA; padded in -> padded 1-ch fp16 out.
// ---------------------------------------------------------------------------
__global__ __launch_bounds__(256) void conv8x1_mfma(const _Float16* __restrict__ DP,
                                                    const _Float16* __restrict__ WF,
                                                    const float* __restrict__ bias,
                                                    _Float16* __restrict__ F)
{
    __shared__ _Float16 Wr[16 * 29 * 8];
    const int tid = threadIdx.x;
    for (int i = tid; i < 16 * 29; i += 256) ((half8*)Wr)[i] = ((const half8*)WF)[i];
    __syncthreads();

    const int b = ((blockIdx.x & 7) << 10) | (blockIdx.x >> 3);  // 8192 blocks
    const int h0 = (b & 63) << 1;
    const int d  = b >> 6;
    const int lane = tid & 63;
    const int wv   = tid >> 6;
    const int col  = lane & 15;
    const int q    = lane >> 4;

    half8 af[7];
    #pragma unroll
    for (int c = 0; c < 7; ++c)
        af[c] = *(const half8*)&Wr[(col * 29 + (c * 4 + q)) * 8];

    const int base0 = ((d + 1) * PD + (h0 + 1)) * PD + 1 + wv * 32 + col;
    const _Float16* p[7];
    #pragma unroll
    for (int c = 0; c < 7; ++c) {
        const int tap = min(c * 4 + q, 26);
        const int dz = tap / 9, r9 = tap - dz * 9;
        const int dy = r9 / 3,  dx = r9 - dy * 3;
        p[c] = DP + (size_t)(base0 + ((dz - 1) * PD + (dy - 1)) * PD + (dx - 1)) * 8;
    }

    const float b0 = bias[0];
    #pragma unroll
    for (int r = 0; r < 2; ++r) {
        #pragma unroll
        for (int t2 = 0; t2 < 2; ++t2) {
            float4v acc = {0.0f, 0.0f, 0.0f, 0.0f};
            #pragma unroll
            for (int c = 0; c < 7; ++c) {
                const half8 bv = *(const half8*)(p[c] + (r * PD + t2 * 16) * 8);
                acc = __builtin_amdgcn_mfma_f32_16x16x32_f16(af[c], bv, acc, 0, 0, 0);
            }
            if (q == 0)
                F[base0 + r * PD + t2 * 16] = (_Float16)(acc[0] + b0);
        }
    }
}

// ---------------------------------------------------------------------------
// 8 -> 27 conv + L1 normalize via MFMA; ROWS=4, LDS-tiled B input.
// Stage 3z x 6y x 130x x 8ch halo tile (37,440 B) + weights (14,848 B);
// B fragments read via ds_read_b128 at 7 precomputed per-lane bases with
// compile-time offsets. Addresses/data bit-identical to the global path.
// q==3 hi half4 covers taps 28..31 — all pad, store skipped.
// ---------------------------------------------------------------------------
__global__ __launch_bounds__(256) void conv8x27n_mfma(const _Float16* __restrict__ HP,
                                                      const _Float16* __restrict__ WF,
                                                      _Float16* __restrict__ WB)
{
    __shared__ _Float16 Wr[32 * 29 * 8];      // 14,848 B
    __shared__ _Float16 T[3 * 6 * 130 * 8];   // 37,440 B: [dz(3)][yy(6)][xs(130)][ch(8)]
    const int tid = threadIdx.x;

    const int b = ((blockIdx.x & 7) << 9) | (blockIdx.x >> 3);  // 4096 blocks
    const int h0 = (b & 31) << 2;
    const int d  = b >> 5;

    for (int i = tid; i < 32 * 29; i += 256) ((half8*)Wr)[i] = ((const half8*)WF)[i];
    // stage tile: rows (d+dz, h0+yy), yy in [0,6), x in [0,130)
    for (int i = tid; i < 3 * 6 * 130; i += 256) {
        const int dz  = i / 780;
        const int rem = i - dz * 780;
        const int yy  = rem / 130;
        const int xs  = rem - yy * 130;
        ((half8*)T)[i] =
            *(const half8*)&HP[((size_t)((d + dz) * PD + (h0 + yy)) * PD + xs) * 8];
    }
    __syncthreads();

    const int lane = tid & 63;
    const int wv   = tid >> 6;
    const int col  = lane & 15;
    const int q    = lane >> 4;

    half8 af[2][7];
    #pragma unroll
    for (int t = 0; t < 2; ++t)
        #pragma unroll
        for (int c = 0; c < 7; ++c)
            af[t][c] = *(const half8*)&Wr[((t * 16 + col) * 29 + (c * 4 + q)) * 8];

    // per-lane LDS base (halves index) for each tap-column c
    int lb[7];
    #pragma unroll
    for (int c = 0; c < 7; ++c) {
        const int tap = min(c * 4 + q, 26);
        const int dz = tap / 9, r9 = tap - dz * 9;
        const int dy = r9 / 3,  dx = r9 - dy * 3;
        lb[c] = ((dz * 6 + dy) * 130 + wv * 32 + col + dx) * 8;
    }

    #pragma unroll
    for (int r = 0; r < 4; ++r) {
        #pragma unroll
        for (int t2 = 0; t2 < 2; ++t2) {
            float4v acc0 = {0.0f, 0.0f, 0.0f, 0.0f};
            float4v acc1 = {0.0f, 0.0f, 0.0f, 0.0f};
            #pragma unroll
            for (int c = 0; c < 7; ++c) {
                const half8 bv = *(const half8*)&T[lb[c] + (r * 130 + t2 * 16) * 8];
                acc0 = __builtin_amdgcn_mfma_f32_16x16x32_f16(af[0][c], bv, acc0, 0, 0, 0);
                acc1 = __builtin_amdgcn_mfma_f32_16x16x32_f16(af[1][c], bv, acc1, 0, 0, 0);
            }

            float s = 0.0f;
            #pragma unroll
            for (int rr = 0; rr < 4; ++rr) {
                s += fabsf(acc0[rr]);
                if (16 + q * 4 + rr < 27) s += fabsf(acc1[rr]);
            }
            s += __shfl_xor(s, 16);
            s += __shfl_xor(s, 32);
            const float rcp = 1.0f / fmaxf(s, 1e-12f);

            const int vox = (d << 14) + ((h0 + r) << 7) + wv * 32 + t2 * 16 + col;
            const size_t base = (size_t)vox * 28;
            half4 o0, o1;
            #pragma unroll
            for (int rr = 0; rr < 4; ++rr) {
                o0[rr] = (_Float16)(acc0[rr] * rcp);
                o1[rr] = (_Float16)(acc1[rr] * rcp);   // pad rows produce 0
            }
            *(half4*)&WB[base + q * 4] = o0;
            if (q < 3)
                *(half4*)&WB[base + 16 + q * 4] = o1;  // q==3: taps 28..31, all pad
        }
    }
}

// ---------------------------------------------------------------------------
// Adaptive stencil, 8ch padded interleaved in/out; LDS-tiled input.
// (R3-verified form: stage first, then W loads after the barrier.)
// ---------------------------------------------------------------------------
__global__ __launch_bounds__(256) void aconv8i(const _Float16* __restrict__ in,
                                               const _Float16* __restrict__ wb,
                                               _Float16* __restrict__ out)
{
    __shared__ _Float16 T[12 * 130 * 8];     // [dz(3)][yy(4)][xslot(130)][ch(8)]
    const int b = ((blockIdx.x & 7) << 10) | (blockIdx.x >> 3);  // 8192 blocks
    const int h0 = (b & 63) << 1;
    const int d  = b >> 6;
    const int tid = threadIdx.x;

    // stage: rows (d+dz, h0+yy) padded, full x range [0,130)
    for (int i = tid; i < 12 * 130; i += 256) {
        const int dz  = i / 520;
        const int rem = i - dz * 520;
        const int yy  = rem / 130;
        const int xs  = rem - yy * 130;
        ((half8*)T)[i] =
            *(const half8*)&in[((size_t)((d + dz) * PD + (h0 + yy)) * PD + xs) * 8];
    }
    __syncthreads();

    const int x   = tid & 127;
    const int ly  = tid >> 7;                 // 0/1: which of the 2 y-rows
    const int idx = b * 256 + tid;            // == (d<<14) + ((h0+ly)<<7) + x

    const size_t wbb = (size_t)idx * 28;
    half4 W[7];
    #pragma unroll
    for (int k = 0; k < 7; ++k) W[k] = *(const half4*)(wb + wbb + k * 4);

    half2v a4[4];
    #pragma unroll
    for (int j = 0; j < 4; ++j) a4[j] = half2v{};

    #pragma unroll
    for (int dz = 0; dz < 3; dz++) {
        #pragma unroll
        for (int dy = 0; dy < 3; dy++) {
            const _Float16* rp = &T[((dz * 4 + (ly + dy)) * 130 + (x + 1)) * 8];
            #pragma unroll
            for (int kw = 0; kw < 3; kw++) {
                const int tap = dz * 9 + dy * 3 + kw;
                const _Float16 wt = W[tap >> 2][tap & 3];
                half2v w2; w2[0] = wt; w2[1] = wt;
                const half8 hv = *(const half8*)(rp + (kw - 1) * 8);
                const half2v* h2 = (const half2v*)&hv;
                #pragma unroll
                for (int j = 0; j < 4; ++j)
                    a4[j] += h2[j] * w2;                 // v_pk_fma_f16
            }
        }
    }

    const int s0 = ((d + 1) * PD + (h0 + ly + 1)) * PD + (x + 1);
    half8 o;
    #pragma unroll
    for (int j = 0; j < 4; ++j) { o[2 * j] = a4[j][0]; o[2 * j + 1] = a4[j][1]; }
    *(half8*)&out[(size_t)s0 * 8] = o;
}

// ---------------------------------------------------------------------------
// Adaptive stencil, 1ch padded fp16 in; fp32 math. WB stride 28.
// (R3-verified global-read form.)
// TANH=false: padded fp16 out. TANH=true: planar fp32 out (final).
// ---------------------------------------------------------------------------
template<bool TANH>
__global__ __launch_bounds__(256) void aconv1h(const _Float16* __restrict__ in,
                                               const _Float16* __restrict__ wb,
                                               _Float16* __restrict__ outh,
                                               float* __restrict__ outf)
{
    const int b = ((blockIdx.x & 7) << 10) | (blockIdx.x >> 3);
    const int idx = b * 256 + threadIdx.x;
    const int w = idx & 127;
    const int h = (idx >> 7) & 127;
    const int d = idx >> 14;

    const size_t wbb = (size_t)idx * 28;
    half4 W[7];
    #pragma unroll
    for (int k = 0; k < 7; ++k) W[k] = *(const half4*)(wb + wbb + k * 4);

    const int s0 = ((d + 1) * PD + (h + 1)) * PD + (w + 1);

    float acc = 0.0f;
    #pragma unroll
    for (int dz = 0; dz < 3; dz++) {
        #pragma unroll
        for (int dy = 0; dy < 3; dy++) {
            const _Float16* rp = in + s0 + ((dz - 1) * PD + (dy - 1)) * PD;
            #pragma unroll
            for (int kw = 0; kw < 3; kw++) {
                const int tap = dz * 9 + dy * 3 + kw;
                const _Float16 wt = W[tap >> 2][tap & 3];
                acc = fmaf((float)rp[kw - 1], (float)wt, acc);
            }
        }
    }

    if (TANH) outf[idx] = tanhf(acc);
    else      outh[s0] = (_Float16)acc;
}

// ---------------------------------------------------------------------------
// ws layout (~192 MiB): P0 | P1 (33.5 MiB padded 8-ch each) | WB (112 MiB)
//   | F1 | G1 | F2 (4.2 MiB padded 1-ch each) | WF (preformatted weights).
// WF halves: [0]=ac1_w1 [3712]=ac2_w1 [7424]=ac3_w1 [11136]=out_w
//   [14848]=mid_w [18560]=ac1_w2 [25984]=ac2_w2 [33408]=ac3_w2
// ---------------------------------------------------------------------------
extern "C" void kernel_launch(void* const* d_in, const int* in_sizes, int n_in,
                              void* d_out, int out_size, void* d_ws, size_t ws_size,
                              hipStream_t stream)
{
    const float* x      = (const float*)d_in[0];
    const float* ac1_w1 = (const float*)d_in[1];
    const float* ac1_b1 = (const float*)d_in[2];
    const float* ac1_w2 = (const float*)d_in[3];
    const float* ac2_w1 = (const float*)d_in[4];
    const float* ac2_b1 = (const float*)d_in[5];
    const float* ac2_w2 = (const float*)d_in[6];
    const float* ac3_w1 = (const float*)d_in[7];
    const float* ac3_b1 = (const float*)d_in[8];
    const float* ac3_w2 = (const float*)d_in[9];
    const float* mid_w  = (const float*)d_in[10];
    const float* mid_b  = (const float*)d_in[11];
    const float* out_w  = (const float*)d_in[12];
    const float* out_b  = (const float*)d_in[13];
    float* out = (float*)d_out;

    char* ws = (char*)d_ws;
    const size_t PS8 = (size_t)PD * PD * PD * 8 * 2;   // 35,152,000 B
    const size_t PS1 = (size_t)PD * PD * PD * 2;       //  4,394,000 B
    const size_t WBsz = (size_t)VOX * 28 * 2;          // 117,440,512 B
    _Float16* P0 = (_Float16*)(ws);
    _Float16* P1 = (_Float16*)(ws + PS8);
    _Float16* WB = (_Float16*)(ws + 2 * PS8);
    _Float16* F1 = (_Float16*)(ws + 2 * PS8 + WBsz);
    _Float16* G1 = (_Float16*)(ws + 2 * PS8 + WBsz + PS1);
    _Float16* F2 = (_Float16*)(ws + 2 * PS8 + WBsz + 2 * PS1);
    _Float16* WF = (_Float16*)(ws + 2 * PS8 + WBsz + 3 * PS1);
    _Float16* WF8_1  = WF;
    _Float16* WF8_2  = WF + 3712;
    _Float16* WF8_3  = WF + 7424;
    _Float16* WFo    = WF + 11136;
    _Float16* WFmid  = WF + 14848;
    _Float16* WF27_1 = WF + 18560;
    _Float16* WF27_2 = WF + 25984;
    _Float16* WF27_3 = WF + 33408;

    const dim3 blk(256);
    const dim3 gridT(VOX / 256);               // cast, aconv: 8192 blocks
    const dim3 gridM(VOX / 256);               // ROWS=2 MFMA convs: 8192 blocks
    const dim3 gridM4(VOX / 512);              // conv8x27n (ROWS=4): 4096 blocks
    const dim3 gridZ((PD * PD + 255) / 256);   // zero_halo: 67 blocks

    zero_halo<8><<<gridZ, blk, 0, stream>>>(P0);
    zero_halo<8><<<gridZ, blk, 0, stream>>>(P1);
    zero_halo<1><<<gridZ, blk, 0, stream>>>(F1);
    zero_halo<1><<<gridZ, blk, 0, stream>>>(G1);
    zero_halo<1><<<gridZ, blk, 0, stream>>>(F2);
    preformat<<<dim3(8), blk, 0, stream>>>(ac1_w1, ac2_w1, ac3_w1, out_w, mid_w,
                                           ac1_w2, ac2_w2, ac3_w2, WF);

    // ---- block 1 ----
    cast_hp<<<gridT, blk, 0, stream>>>(x, P0);                       // X16 = P0
    conv8x8_mfma<true ><<<gridM, blk, 0, stream>>>(P0, WF8_1, ac1_b1, P1);   // H1
    conv8x27n_mfma<<<gridM4, blk, 0, stream>>>(P1, WF27_1, WB);
    aconv8i<<<gridT, blk, 0, stream>>>(P0, WB, P1);                  // (H1 dead)
    aconv8i<<<gridT, blk, 0, stream>>>(P1, WB, P0);
    aconv8i<<<gridT, blk, 0, stream>>>(P0, WB, P1);                  // C1 = P1
    // ---- mid conv ----
    conv8x8_mfma<false><<<gridM, blk, 0, stream>>>(P1, WFmid, mid_b, P0);    // M = P0
    // ---- block 2 ----
    conv8x8_mfma<true ><<<gridM, blk, 0, stream>>>(P0, WF8_2, ac2_b1, P1);   // H2
    conv8x27n_mfma<<<gridM4, blk, 0, stream>>>(P1, WF27_2, WB);
    aconv8i<<<gridT, blk, 0, stream>>>(P0, WB, P1);
    aconv8i<<<gridT, blk, 0, stream>>>(P1, WB, P0);
    aconv8i<<<gridT, blk, 0, stream>>>(P0, WB, P1);                  // mid2 = P1
    // ---- block 3 (weights from mid2 = P1) ----
    conv8x8_mfma<true ><<<gridM, blk, 0, stream>>>(P1, WF8_3, ac3_b1, P0);   // H3
    conv8x27n_mfma<<<gridM4, blk, 0, stream>>>(P0, WF27_3, WB);
    conv8x1_mfma<<<gridM, blk, 0, stream>>>(P1, WFo, out_b, F1);
    aconv1h<false><<<gridT, blk, 0, stream>>>(F1, WB, G1, nullptr);
    aconv1h<false><<<gridT, blk, 0, stream>>>(G1, WB, F2, nullptr);
    aconv1h<true ><<<gridT, blk, 0, stream>>>(F2, WB, nullptr, out);
}

// Round 7
// 728.175 us; speedup vs baseline: 1.0571x; 1.0180x over previous
//
#include <hip/hip_runtime.h>
#include <math.h>

#define DSZ 128
#define VOX (DSZ*DSZ*DSZ)  // 2,097,152 voxels
#define PD  130            // padded dim (halo 1 on all 6 faces)

typedef _Float16 half8 __attribute__((ext_vector_type(8)));
typedef _Float16 half4 __attribute__((ext_vector_type(4)));
typedef _Float16 half2v __attribute__((ext_vector_type(2)));
typedef float float4v __attribute__((ext_vector_type(4)));

// Halo-padded tensors: slot(z,y,x) = ((z+1)*130 + (y+1))*130 + (x+1),
// z,y,x in [-1,128]. 8-ch interleaved: halves = slot*8 (33.5 MiB).
// 1-ch: halves = slot (4.2 MiB). Halos zeroed once; interior-only writes.
// WB: interleaved [vox][28] halves (27 taps + 1 pad), 112 MiB.

// ---------------------------------------------------------------------------
// Zero the halo of a padded tensor (ws is re-poisoned before every call).
// ---------------------------------------------------------------------------
template<int CH>
__global__ __launch_bounds__(256) void zero_halo(_Float16* __restrict__ P)
{
    const int t = blockIdx.x * 256 + threadIdx.x;   // (zp,yp) row in [0,130)^2
    if (t >= PD * PD) return;
    const int zp = t / PD;
    const int yp = t - zp * PD;
    _Float16* row = P + (size_t)t * PD * CH;
    if (zp == 0 || zp == PD - 1 || yp == 0 || yp == PD - 1) {
        if (CH == 8) {
            half8 zz = {};
            for (int x = 0; x < PD; ++x) *(half8*)&row[x * 8] = zz;
        } else {
            for (int x = 0; x < PD; ++x) row[x] = (_Float16)0.0f;
        }
    } else {
        if (CH == 8) {
            half8 zz = {};
            *(half8*)&row[0] = zz;
            *(half8*)&row[(PD - 1) * 8] = zz;
        } else {
            row[0] = (_Float16)0.0f;
            row[PD - 1] = (_Float16)0.0f;
        }
    }
}

// ---------------------------------------------------------------------------
// Preformat conv weights -> fp16 [oc][tap(stride 29)][ic], once per launch.
// Blocks: 0..2 = ac{1,2,3}_w1; 3 = out_w; 4 = mid_w; 5..7 = ac{1,2,3}_w2.
// ---------------------------------------------------------------------------
__global__ __launch_bounds__(256) void preformat(const float* __restrict__ w1a, const float* __restrict__ w1b,
                                                 const float* __restrict__ w1c, const float* __restrict__ outw,
                                                 const float* __restrict__ midw,
                                                 const float* __restrict__ w2a, const float* __restrict__ w2b,
                                                 const float* __restrict__ w2c, _Float16* __restrict__ WF)
{
    const int bid = blockIdx.x, tid = threadIdx.x;
    const float* src;
    _Float16* dst;
    int nelem, sz;
    if (bid < 3)       { src = bid == 0 ? w1a : bid == 1 ? w1b : w1c; dst = WF + bid * 3712; nelem = 8 * 216; sz = 16 * 29; }
    else if (bid == 3) { src = outw; dst = WF + 3 * 3712; nelem = 216;     sz = 16 * 29; }
    else if (bid == 4) { src = midw; dst = WF + 4 * 3712; nelem = 8 * 216; sz = 16 * 29; }
    else               { src = bid == 5 ? w2a : bid == 6 ? w2b : w2c; dst = WF + 5 * 3712 + (bid - 5) * 7424; nelem = 27 * 216; sz = 32 * 29; }
    for (int i = tid; i < sz; i += 256) ((half8*)dst)[i] = half8{};
    __syncthreads();
    for (int i = tid; i < nelem; i += 256) {
        const int oc = i / 216;
        const int rem = i - oc * 216;
        const int ic = rem / 27;
        const int tap = rem - ic * 27;
        dst[(oc * 29 + tap) * 8 + ic] = (_Float16)src[i];
    }
}

// ---------------------------------------------------------------------------
// Cast planar fp32 (8ch) -> halo-padded interleaved fp16 (interior only).
// ---------------------------------------------------------------------------
__global__ __launch_bounds__(256) void cast_hp(const float* __restrict__ in,
                                               _Float16* __restrict__ hp)
{
    const int idx = blockIdx.x * 256 + threadIdx.x;
    const int w = idx & 127;
    const int h = (idx >> 7) & 127;
    const int d = idx >> 14;
    half8 v;
    #pragma unroll
    for (int ic = 0; ic < 8; ++ic) v[ic] = (_Float16)in[(size_t)ic * VOX + idx];
    const int slot = ((d + 1) * PD + (h + 1)) * PD + (w + 1);
    *(half8*)&hp[(size_t)slot * 8] = v;
}

// ---------------------------------------------------------------------------
// Dense 3x3x3 conv 8->8 (+bias, opt relu) via MFMA; padded in/out, ROWS=2.
// ---------------------------------------------------------------------------
template<bool RELU>
__global__ __launch_bounds__(256) void conv8x8_mfma(const _Float16* __restrict__ DP,
                                                    const _Float16* __restrict__ WF,
                                                    const float* __restrict__ bias,
                                                    _Float16* __restrict__ HO)
{
    __shared__ _Float16 Wr[16 * 29 * 8];
    const int tid = threadIdx.x;
    for (int i = tid; i < 16 * 29; i += 256) ((half8*)Wr)[i] = ((const half8*)WF)[i];
    __syncthreads();

    const int b = ((blockIdx.x & 7) << 10) | (blockIdx.x >> 3);  // 8192 blocks
    const int h0 = (b & 63) << 1;
    const int d  = b >> 6;
    const int lane = tid & 63;
    const int wv   = tid >> 6;
    const int col  = lane & 15;
    const int q    = lane >> 4;

    half8 af[7];
    #pragma unroll
    for (int c = 0; c < 7; ++c)
        af[c] = *(const half8*)&Wr[(col * 29 + (c * 4 + q)) * 8];

    const int base0 = ((d + 1) * PD + (h0 + 1)) * PD + 1 + wv * 32 + col;
    const _Float16* p[7];
    #pragma unroll
    for (int c = 0; c < 7; ++c) {
        const int tap = min(c * 4 + q, 26);
        const int dz = tap / 9, r9 = tap - dz * 9;
        const int dy = r9 / 3,  dx = r9 - dy * 3;
        p[c] = DP + (size_t)(base0 + ((dz - 1) * PD + (dy - 1)) * PD + (dx - 1)) * 8;
    }

    #pragma unroll
    for (int r = 0; r < 2; ++r) {
        #pragma unroll
        for (int t2 = 0; t2 < 2; ++t2) {
            float4v acc = {0.0f, 0.0f, 0.0f, 0.0f};
            #pragma unroll
            for (int c = 0; c < 7; ++c) {
                const half8 bv = *(const half8*)(p[c] + (r * PD + t2 * 16) * 8);
                acc = __builtin_amdgcn_mfma_f32_16x16x32_f16(af[c], bv, acc, 0, 0, 0);
            }
            if (q < 2) {
                const float4v bl = ((const float4v*)bias)[q];
                half4 hv;
                #pragma unroll
                for (int rr = 0; rr < 4; ++rr) {
                    float v = acc[rr] + bl[rr];
                    if (RELU) v = fmaxf(v, 0.0f);
                    hv[rr] = (_Float16)v;
                }
                *(half4*)&HO[(size_t)(base0 + r * PD + t2 * 16) * 8 + q * 4] = hv;
            }
        }
    }
}

// ---------------------------------------------------------------------------
// Dense 3x3x3 conv 8->1 (+bias) via MFMA; padded in -> padded 1-ch fp16 out.
// ---------------------------------------------------------------------------
__global__ __launch_bounds__(256) void conv8x1_mfma(const _Float16* __restrict__ DP,
                                                    const _Float16* __restrict__ WF,
                                                    const float* __restrict__ bias,
                                                    _Float16* __restrict__ F)
{
    __shared__ _Float16 Wr[16 * 29 * 8];
    const int tid = threadIdx.x;
    for (int i = tid; i < 16 * 29; i += 256) ((half8*)Wr)[i] = ((const half8*)WF)[i];
    __syncthreads();

    const int b = ((blockIdx.x & 7) << 10) | (blockIdx.x >> 3);  // 8192 blocks
    const int h0 = (b & 63) << 1;
    const int d  = b >> 6;
    const int lane = tid & 63;
    const int wv   = tid >> 6;
    const int col  = lane & 15;
    const int q    = lane >> 4;

    half8 af[7];
    #pragma unroll
    for (int c = 0; c < 7; ++c)
        af[c] = *(const half8*)&Wr[(col * 29 + (c * 4 + q)) * 8];

    const int base0 = ((d + 1) * PD + (h0 + 1)) * PD + 1 + wv * 32 + col;
    const _Float16* p[7];
    #pragma unroll
    for (int c = 0; c < 7; ++c) {
        const int tap = min(c * 4 + q, 26);
        const int dz = tap / 9, r9 = tap - dz * 9;
        const int dy = r9 / 3,  dx = r9 - dy * 3;
        p[c] = DP + (size_t)(base0 + ((dz - 1) * PD + (dy - 1)) * PD + (dx - 1)) * 8;
    }

    const float b0 = bias[0];
    #pragma unroll
    for (int r = 0; r < 2; ++r) {
        #pragma unroll
        for (int t2 = 0; t2 < 2; ++t2) {
            float4v acc = {0.0f, 0.0f, 0.0f, 0.0f};
            #pragma unroll
            for (int c = 0; c < 7; ++c) {
                const half8 bv = *(const half8*)(p[c] + (r * PD + t2 * 16) * 8);
                acc = __builtin_amdgcn_mfma_f32_16x16x32_f16(af[c], bv, acc, 0, 0, 0);
            }
            if (q == 0)
                F[base0 + r * PD + t2 * 16] = (_Float16)(acc[0] + b0);
        }
    }
}

// ---------------------------------------------------------------------------
// 8 -> 27 conv + L1 normalize via MFMA; ROWS=4, LDS-tiled B input.
// (R5-verified form.)
// ---------------------------------------------------------------------------
__global__ __launch_bounds__(256) void conv8x27n_mfma(const _Float16* __restrict__ HP,
                                                      const _Float16* __restrict__ WF,
                                                      _Float16* __restrict__ WB)
{
    __shared__ _Float16 Wr[32 * 29 * 8];      // 14,848 B
    __shared__ _Float16 T[3 * 6 * 130 * 8];   // 37,440 B: [dz(3)][yy(6)][xs(130)][ch(8)]
    const int tid = threadIdx.x;

    const int b = ((blockIdx.x & 7) << 9) | (blockIdx.x >> 3);  // 4096 blocks
    const int h0 = (b & 31) << 2;
    const int d  = b >> 5;

    for (int i = tid; i < 32 * 29; i += 256) ((half8*)Wr)[i] = ((const half8*)WF)[i];
    // stage tile: rows (d+dz, h0+yy), yy in [0,6), x in [0,130)
    for (int i = tid; i < 3 * 6 * 130; i += 256) {
        const int dz  = i / 780;
        const int rem = i - dz * 780;
        const int yy  = rem / 130;
        const int xs  = rem - yy * 130;
        ((half8*)T)[i] =
            *(const half8*)&HP[((size_t)((d + dz) * PD + (h0 + yy)) * PD + xs) * 8];
    }
    __syncthreads();

    const int lane = tid & 63;
    const int wv   = tid >> 6;
    const int col  = lane & 15;
    const int q    = lane >> 4;

    half8 af[2][7];
    #pragma unroll
    for (int t = 0; t < 2; ++t)
        #pragma unroll
        for (int c = 0; c < 7; ++c)
            af[t][c] = *(const half8*)&Wr[((t * 16 + col) * 29 + (c * 4 + q)) * 8];

    // per-lane LDS base (halves index) for each tap-column c
    int lb[7];
    #pragma unroll
    for (int c = 0; c < 7; ++c) {
        const int tap = min(c * 4 + q, 26);
        const int dz = tap / 9, r9 = tap - dz * 9;
        const int dy = r9 / 3,  dx = r9 - dy * 3;
        lb[c] = ((dz * 6 + dy) * 130 + wv * 32 + col + dx) * 8;
    }

    #pragma unroll
    for (int r = 0; r < 4; ++r) {
        #pragma unroll
        for (int t2 = 0; t2 < 2; ++t2) {
            float4v acc0 = {0.0f, 0.0f, 0.0f, 0.0f};
            float4v acc1 = {0.0f, 0.0f, 0.0f, 0.0f};
            #pragma unroll
            for (int c = 0; c < 7; ++c) {
                const half8 bv = *(const half8*)&T[lb[c] + (r * 130 + t2 * 16) * 8];
                acc0 = __builtin_amdgcn_mfma_f32_16x16x32_f16(af[0][c], bv, acc0, 0, 0, 0);
                acc1 = __builtin_amdgcn_mfma_f32_16x16x32_f16(af[1][c], bv, acc1, 0, 0, 0);
            }

            float s = 0.0f;
            #pragma unroll
            for (int rr = 0; rr < 4; ++rr) {
                s += fabsf(acc0[rr]);
                if (16 + q * 4 + rr < 27) s += fabsf(acc1[rr]);
            }
            s += __shfl_xor(s, 16);
            s += __shfl_xor(s, 32);
            const float rcp = 1.0f / fmaxf(s, 1e-12f);

            const int vox = (d << 14) + ((h0 + r) << 7) + wv * 32 + t2 * 16 + col;
            const size_t base = (size_t)vox * 28;
            half4 o0, o1;
            #pragma unroll
            for (int rr = 0; rr < 4; ++rr) {
                o0[rr] = (_Float16)(acc0[rr] * rcp);
                o1[rr] = (_Float16)(acc1[rr] * rcp);   // pad rows produce 0
            }
            *(half4*)&WB[base + q * 4] = o0;
            if (q < 3)
                *(half4*)&WB[base + 16 + q * 4] = o1;  // q==3: taps 28..31, all pad
        }
    }
}

// ---------------------------------------------------------------------------
// Adaptive stencil, 8ch padded interleaved in/out; ROLLING-Z LDS ring.
// Block owns a 2y x 128x column and walks 8 z-slices; 4-slot ring of
// 4y x 130x x 8ch slices (33,280 B). Per step: stage 1 new slice (slot
// (z+3)&3, disjoint from the 3 read slots), compute, 1 barrier.
// Staging redundancy 6x -> 2.5x vs the per-block-tile version.
// Per-voxel tap order (dz,dy,kw) identical — bit-exact.
// ---------------------------------------------------------------------------
__global__ __launch_bounds__(256) void aconv8i(const _Float16* __restrict__ in,
                                               const _Float16* __restrict__ wb,
                                               _Float16* __restrict__ out)
{
    __shared__ _Float16 T[4][4 * 130 * 8];   // ring: [slot][(yy*130+xs)*8+ch]
    const int b = ((blockIdx.x & 7) << 7) | (blockIdx.x >> 3);  // 1024 blocks
    const int h0 = (b & 63) << 1;
    const int d0 = (b >> 6) << 3;            // chunk of 8 z-slices
    const int tid = threadIdx.x;

    // stage input slice z (unpadded plane index, -1..128) into its ring slot
    auto stage = [&](int z) {
        const int slot = (z + 1) & 3;
        for (int i = tid; i < 4 * 130; i += 256) {
            const int yy = i / 130;
            const int xs = i - yy * 130;
            *(half8*)&T[slot][i * 8] =
                *(const half8*)&in[((size_t)((z + 1) * PD + (h0 + yy)) * PD + xs) * 8];
        }
    };

    stage(d0 - 1); stage(d0); stage(d0 + 1);
    __syncthreads();

    const int x  = tid & 127;
    const int ly = tid >> 7;                  // 0/1: which of the 2 y-rows

    for (int z = d0; z < d0 + 8; ++z) {
        if (z <= d0 + 6) stage(z + 2);        // slot (z+3)&3: holds z-2, not read now

        const int idx = (z << 14) + ((h0 + ly) << 7) + x;
        const size_t wbb = (size_t)idx * 28;
        half4 W[7];
        #pragma unroll
        for (int k = 0; k < 7; ++k) W[k] = *(const half4*)(wb + wbb + k * 4);

        half2v a4[4];
        #pragma unroll
        for (int j = 0; j < 4; ++j) a4[j] = half2v{};

        #pragma unroll
        for (int dz = 0; dz < 3; dz++) {
            const int slot = (z + dz) & 3;    // slice z-1+dz
            #pragma unroll
            for (int dy = 0; dy < 3; dy++) {
                const _Float16* rp = &T[slot][((ly + dy) * 130 + (x + 1)) * 8];
                #pragma unroll
                for (int kw = 0; kw < 3; kw++) {
                    const int tap = dz * 9 + dy * 3 + kw;
                    const _Float16 wt = W[tap >> 2][tap & 3];
                    half2v w2; w2[0] = wt; w2[1] = wt;
                    const half8 hv = *(const half8*)(rp + (kw - 1) * 8);
                    const half2v* h2 = (const half2v*)&hv;
                    #pragma unroll
                    for (int j = 0; j < 4; ++j)
                        a4[j] += h2[j] * w2;             // v_pk_fma_f16
                }
            }
        }

        const int s0 = ((z + 1) * PD + (h0 + ly + 1)) * PD + (x + 1);
        half8 o;
        #pragma unroll
        for (int j = 0; j < 4; ++j) { o[2 * j] = a4[j][0]; o[2 * j + 1] = a4[j][1]; }
        *(half8*)&out[(size_t)s0 * 8] = o;

        __syncthreads();   // reads of slot (z)&3 done before next iter overwrites it
    }
}

// ---------------------------------------------------------------------------
// Adaptive stencil, 1ch padded fp16 in; fp32 math. WB stride 28.
// (R3-verified global-read form.)
// TANH=false: padded fp16 out. TANH=true: planar fp32 out (final).
// ---------------------------------------------------------------------------
template<bool TANH>
__global__ __launch_bounds__(256) void aconv1h(const _Float16* __restrict__ in,
                                               const _Float16* __restrict__ wb,
                                               _Float16* __restrict__ outh,
                                               float* __restrict__ outf)
{
    const int b = ((blockIdx.x & 7) << 10) | (blockIdx.x >> 3);
    const int idx = b * 256 + threadIdx.x;
    const int w = idx & 127;
    const int h = (idx >> 7) & 127;
    const int d = idx >> 14;

    const size_t wbb = (size_t)idx * 28;
    half4 W[7];
    #pragma unroll
    for (int k = 0; k < 7; ++k) W[k] = *(const half4*)(wb + wbb + k * 4);

    const int s0 = ((d + 1) * PD + (h + 1)) * PD + (w + 1);

    float acc = 0.0f;
    #pragma unroll
    for (int dz = 0; dz < 3; dz++) {
        #pragma unroll
        for (int dy = 0; dy < 3; dy++) {
            const _Float16* rp = in + s0 + ((dz - 1) * PD + (dy - 1)) * PD;
            #pragma unroll
            for (int kw = 0; kw < 3; kw++) {
                const int tap = dz * 9 + dy * 3 + kw;
                const _Float16 wt = W[tap >> 2][tap & 3];
                acc = fmaf((float)rp[kw - 1], (float)wt, acc);
            }
        }
    }

    if (TANH) outf[idx] = tanhf(acc);
    else      outh[s0] = (_Float16)acc;
}

// ---------------------------------------------------------------------------
// ws layout (~192 MiB): P0 | P1 (33.5 MiB padded 8-ch each) | WB (112 MiB)
//   | F1 | G1 | F2 (4.2 MiB padded 1-ch each) | WF (preformatted weights).
// WF halves: [0]=ac1_w1 [3712]=ac2_w1 [7424]=ac3_w1 [11136]=out_w
//   [14848]=mid_w [18560]=ac1_w2 [25984]=ac2_w2 [33408]=ac3_w2
// ---------------------------------------------------------------------------
extern "C" void kernel_launch(void* const* d_in, const int* in_sizes, int n_in,
                              void* d_out, int out_size, void* d_ws, size_t ws_size,
                              hipStream_t stream)
{
    const float* x      = (const float*)d_in[0];
    const float* ac1_w1 = (const float*)d_in[1];
    const float* ac1_b1 = (const float*)d_in[2];
    const float* ac1_w2 = (const float*)d_in[3];
    const float* ac2_w1 = (const float*)d_in[4];
    const float* ac2_b1 = (const float*)d_in[5];
    const float* ac2_w2 = (const float*)d_in[6];
    const float* ac3_w1 = (const float*)d_in[7];
    const float* ac3_b1 = (const float*)d_in[8];
    const float* ac3_w2 = (const float*)d_in[9];
    const float* mid_w  = (const float*)d_in[10];
    const float* mid_b  = (const float*)d_in[11];
    const float* out_w  = (const float*)d_in[12];
    const float* out_b  = (const float*)d_in[13];
    float* out = (float*)d_out;

    char* ws = (char*)d_ws;
    const size_t PS8 = (size_t)PD * PD * PD * 8 * 2;   // 35,152,000 B
    const size_t PS1 = (size_t)PD * PD * PD * 2;       //  4,394,000 B
    const size_t WBsz = (size_t)VOX * 28 * 2;          // 117,440,512 B
    _Float16* P0 = (_Float16*)(ws);
    _Float16* P1 = (_Float16*)(ws + PS8);
    _Float16* WB = (_Float16*)(ws + 2 * PS8);
    _Float16* F1 = (_Float16*)(ws + 2 * PS8 + WBsz);
    _Float16* G1 = (_Float16*)(ws + 2 * PS8 + WBsz + PS1);
    _Float16* F2 = (_Float16*)(ws + 2 * PS8 + WBsz + 2 * PS1);
    _Float16* WF = (_Float16*)(ws + 2 * PS8 + WBsz + 3 * PS1);
    _Float16* WF8_1  = WF;
    _Float16* WF8_2  = WF + 3712;
    _Float16* WF8_3  = WF + 7424;
    _Float16* WFo    = WF + 11136;
    _Float16* WFmid  = WF + 14848;
    _Float16* WF27_1 = WF + 18560;
    _Float16* WF27_2 = WF + 25984;
    _Float16* WF27_3 = WF + 33408;

    const dim3 blk(256);
    const dim3 gridT(VOX / 256);               // cast: 8192 blocks
    const dim3 gridM(VOX / 256);               // ROWS=2 MFMA convs: 8192 blocks
    const dim3 gridM4(VOX / 512);              // conv8x27n (ROWS=4): 4096 blocks
    const dim3 gridA(1024);                    // rolling-z aconv8i: 1024 blocks
    const dim3 gridZ((PD * PD + 255) / 256);   // zero_halo: 67 blocks

    zero_halo<8><<<gridZ, blk, 0, stream>>>(P0);
    zero_halo<8><<<gridZ, blk, 0, stream>>>(P1);
    zero_halo<1><<<gridZ, blk, 0, stream>>>(F1);
    zero_halo<1><<<gridZ, blk, 0, stream>>>(G1);
    zero_halo<1><<<gridZ, blk, 0, stream>>>(F2);
    preformat<<<dim3(8), blk, 0, stream>>>(ac1_w1, ac2_w1, ac3_w1, out_w, mid_w,
                                           ac1_w2, ac2_w2, ac3_w2, WF);

    // ---- block 1 ----
    cast_hp<<<gridT, blk, 0, stream>>>(x, P0);                       // X16 = P0
    conv8x8_mfma<true ><<<gridM, blk, 0, stream>>>(P0, WF8_1, ac1_b1, P1);   // H1
    conv8x27n_mfma<<<gridM4, blk, 0, stream>>>(P1, WF27_1, WB);
    aconv8i<<<gridA, blk, 0, stream>>>(P0, WB, P1);                  // (H1 dead)
    aconv8i<<<gridA, blk, 0, stream>>>(P1, WB, P0);
    aconv8i<<<gridA, blk, 0, stream>>>(P0, WB, P1);                  // C1 = P1
    // ---- mid conv ----
    conv8x8_mfma<false><<<gridM, blk, 0, stream>>>(P1, WFmid, mid_b, P0);    // M = P0
    // ---- block 2 ----
    conv8x8_mfma<true ><<<gridM, blk, 0, stream>>>(P0, WF8_2, ac2_b1, P1);   // H2
    conv8x27n_mfma<<<gridM4, blk, 0, stream>>>(P1, WF27_2, WB);
    aconv8i<<<gridA, blk, 0, stream>>>(P0, WB, P1);
    aconv8i<<<gridA, blk, 0, stream>>>(P1, WB, P0);
    aconv8i<<<gridA, blk, 0, stream>>>(P0, WB, P1);                  // mid2 = P1
    // ---- block 3 (weights from mid2 = P1) ----
    conv8x8_mfma<true ><<<gridM, blk, 0, stream>>>(P1, WF8_3, ac3_b1, P0);   // H3
    conv8x27n_mfma<<<gridM4, blk, 0, stream>>>(P0, WF27_3, WB);
    conv8x1_mfma<<<gridM, blk, 0, stream>>>(P1, WFo, out_b, F1);
    aconv1h<false><<<gridT, blk, 0, stream>>>(F1, WB, G1, nullptr);
    aconv1h<false><<<gridT, blk, 0, stream>>>(G1, WB, F2, nullptr);
    aconv1h<true ><<<gridT, blk, 0, stream>>>(F2, WB, nullptr, out);
}

// Round 8
// 725.028 us; speedup vs baseline: 1.0617x; 1.0043x over previous
//
#include <hip/hip_runtime.h>
#include <math.h>

#define DSZ 128
#define VOX (DSZ*DSZ*DSZ)  // 2,097,152 voxels
#define PD  130            // padded dim (halo 1 on all 6 faces)

typedef _Float16 half8 __attribute__((ext_vector_type(8)));
typedef _Float16 half4 __attribute__((ext_vector_type(4)));
typedef _Float16 half2v __attribute__((ext_vector_type(2)));
typedef float float4v __attribute__((ext_vector_type(4)));

// Halo-padded tensors: slot(z,y,x) = ((z+1)*130 + (y+1))*130 + (x+1),
// z,y,x in [-1,128]. 8-ch interleaved: halves = slot*8 (33.5 MiB).
// 1-ch: halves = slot (4.2 MiB). Halos zeroed once; interior-only writes.
// WB: interleaved [vox][28] halves (27 taps + 1 pad), 112 MiB.

// ---------------------------------------------------------------------------
// Zero the halo of a padded tensor (ws is re-poisoned before every call).
// ---------------------------------------------------------------------------
template<int CH>
__global__ __launch_bounds__(256) void zero_halo(_Float16* __restrict__ P)
{
    const int t = blockIdx.x * 256 + threadIdx.x;   // (zp,yp) row in [0,130)^2
    if (t >= PD * PD) return;
    const int zp = t / PD;
    const int yp = t - zp * PD;
    _Float16* row = P + (size_t)t * PD * CH;
    if (zp == 0 || zp == PD - 1 || yp == 0 || yp == PD - 1) {
        if (CH == 8) {
            half8 zz = {};
            for (int x = 0; x < PD; ++x) *(half8*)&row[x * 8] = zz;
        } else {
            for (int x = 0; x < PD; ++x) row[x] = (_Float16)0.0f;
        }
    } else {
        if (CH == 8) {
            half8 zz = {};
            *(half8*)&row[0] = zz;
            *(half8*)&row[(PD - 1) * 8] = zz;
        } else {
            row[0] = (_Float16)0.0f;
            row[PD - 1] = (_Float16)0.0f;
        }
    }
}

// ---------------------------------------------------------------------------
// Preformat conv weights -> fp16 [oc][tap(stride 29)][ic], once per launch.
// Blocks: 0..2 = ac{1,2,3}_w1; 3 = out_w; 4 = mid_w; 5..7 = ac{1,2,3}_w2.
// ---------------------------------------------------------------------------
__global__ __launch_bounds__(256) void preformat(const float* __restrict__ w1a, const float* __restrict__ w1b,
                                                 const float* __restrict__ w1c, const float* __restrict__ outw,
                                                 const float* __restrict__ midw,
                                                 const float* __restrict__ w2a, const float* __restrict__ w2b,
                                                 const float* __restrict__ w2c, _Float16* __restrict__ WF)
{
    const int bid = blockIdx.x, tid = threadIdx.x;
    const float* src;
    _Float16* dst;
    int nelem, sz;
    if (bid < 3)       { src = bid == 0 ? w1a : bid == 1 ? w1b : w1c; dst = WF + bid * 3712; nelem = 8 * 216; sz = 16 * 29; }
    else if (bid == 3) { src = outw; dst = WF + 3 * 3712; nelem = 216;     sz = 16 * 29; }
    else if (bid == 4) { src = midw; dst = WF + 4 * 3712; nelem = 8 * 216; sz = 16 * 29; }
    else               { src = bid == 5 ? w2a : bid == 6 ? w2b : w2c; dst = WF + 5 * 3712 + (bid - 5) * 7424; nelem = 27 * 216; sz = 32 * 29; }
    for (int i = tid; i < sz; i += 256) ((half8*)dst)[i] = half8{};
    __syncthreads();
    for (int i = tid; i < nelem; i += 256) {
        const int oc = i / 216;
        const int rem = i - oc * 216;
        const int ic = rem / 27;
        const int tap = rem - ic * 27;
        dst[(oc * 29 + tap) * 8 + ic] = (_Float16)src[i];
    }
}

// ---------------------------------------------------------------------------
// Cast planar fp32 (8ch) -> halo-padded interleaved fp16 (interior only).
// ---------------------------------------------------------------------------
__global__ __launch_bounds__(256) void cast_hp(const float* __restrict__ in,
                                               _Float16* __restrict__ hp)
{
    const int idx = blockIdx.x * 256 + threadIdx.x;
    const int w = idx & 127;
    const int h = (idx >> 7) & 127;
    const int d = idx >> 14;
    half8 v;
    #pragma unroll
    for (int ic = 0; ic < 8; ++ic) v[ic] = (_Float16)in[(size_t)ic * VOX + idx];
    const int slot = ((d + 1) * PD + (h + 1)) * PD + (w + 1);
    *(half8*)&hp[(size_t)slot * 8] = v;
}

// ---------------------------------------------------------------------------
// Dense 3x3x3 conv 8->8 (+bias, opt relu) via MFMA; padded in/out, ROWS=2.
// ---------------------------------------------------------------------------
template<bool RELU>
__global__ __launch_bounds__(256) void conv8x8_mfma(const _Float16* __restrict__ DP,
                                                    const _Float16* __restrict__ WF,
                                                    const float* __restrict__ bias,
                                                    _Float16* __restrict__ HO)
{
    __shared__ _Float16 Wr[16 * 29 * 8];
    const int tid = threadIdx.x;
    for (int i = tid; i < 16 * 29; i += 256) ((half8*)Wr)[i] = ((const half8*)WF)[i];
    __syncthreads();

    const int b = ((blockIdx.x & 7) << 10) | (blockIdx.x >> 3);  // 8192 blocks
    const int h0 = (b & 63) << 1;
    const int d  = b >> 6;
    const int lane = tid & 63;
    const int wv   = tid >> 6;
    const int col  = lane & 15;
    const int q    = lane >> 4;

    half8 af[7];
    #pragma unroll
    for (int c = 0; c < 7; ++c)
        af[c] = *(const half8*)&Wr[(col * 29 + (c * 4 + q)) * 8];

    const int base0 = ((d + 1) * PD + (h0 + 1)) * PD + 1 + wv * 32 + col;
    const _Float16* p[7];
    #pragma unroll
    for (int c = 0; c < 7; ++c) {
        const int tap = min(c * 4 + q, 26);
        const int dz = tap / 9, r9 = tap - dz * 9;
        const int dy = r9 / 3,  dx = r9 - dy * 3;
        p[c] = DP + (size_t)(base0 + ((dz - 1) * PD + (dy - 1)) * PD + (dx - 1)) * 8;
    }

    #pragma unroll
    for (int r = 0; r < 2; ++r) {
        #pragma unroll
        for (int t2 = 0; t2 < 2; ++t2) {
            float4v acc = {0.0f, 0.0f, 0.0f, 0.0f};
            #pragma unroll
            for (int c = 0; c < 7; ++c) {
                const half8 bv = *(const half8*)(p[c] + (r * PD + t2 * 16) * 8);
                acc = __builtin_amdgcn_mfma_f32_16x16x32_f16(af[c], bv, acc, 0, 0, 0);
            }
            if (q < 2) {
                const float4v bl = ((const float4v*)bias)[q];
                half4 hv;
                #pragma unroll
                for (int rr = 0; rr < 4; ++rr) {
                    float v = acc[rr] + bl[rr];
                    if (RELU) v = fmaxf(v, 0.0f);
                    hv[rr] = (_Float16)v;
                }
                *(half4*)&HO[(size_t)(base0 + r * PD + t2 * 16) * 8 + q * 4] = hv;
            }
        }
    }
}

// ---------------------------------------------------------------------------
// Dense 3x3x3 conv 8->1 (+bias) via MFMA; padded in -> padded 1-ch fp16 out.
// ---------------------------------------------------------------------------
__global__ __launch_bounds__(256) void conv8x1_mfma(const _Float16* __restrict__ DP,
                                                    const _Float16* __restrict__ WF,
                                                    const float* __restrict__ bias,
                                                    _Float16* __restrict__ F)
{
    __shared__ _Float16 Wr[16 * 29 * 8];
    const int tid = threadIdx.x;
    for (int i = tid; i < 16 * 29; i += 256) ((half8*)Wr)[i] = ((const half8*)WF)[i];
    __syncthreads();

    const int b = ((blockIdx.x & 7) << 10) | (blockIdx.x >> 3);  // 8192 blocks
    const int h0 = (b & 63) << 1;
    const int d  = b >> 6;
    const int lane = tid & 63;
    const int wv   = tid >> 6;
    const int col  = lane & 15;
    const int q    = lane >> 4;

    half8 af[7];
    #pragma unroll
    for (int c = 0; c < 7; ++c)
        af[c] = *(const half8*)&Wr[(col * 29 + (c * 4 + q)) * 8];

    const int base0 = ((d + 1) * PD + (h0 + 1)) * PD + 1 + wv * 32 + col;
    const _Float16* p[7];
    #pragma unroll
    for (int c = 0; c < 7; ++c) {
        const int tap = min(c * 4 + q, 26);
        const int dz = tap / 9, r9 = tap - dz * 9;
        const int dy = r9 / 3,  dx = r9 - dy * 3;
        p[c] = DP + (size_t)(base0 + ((dz - 1) * PD + (dy - 1)) * PD + (dx - 1)) * 8;
    }

    const float b0 = bias[0];
    #pragma unroll
    for (int r = 0; r < 2; ++r) {
        #pragma unroll
        for (int t2 = 0; t2 < 2; ++t2) {
            float4v acc = {0.0f, 0.0f, 0.0f, 0.0f};
            #pragma unroll
            for (int c = 0; c < 7; ++c) {
                const half8 bv = *(const half8*)(p[c] + (r * PD + t2 * 16) * 8);
                acc = __builtin_amdgcn_mfma_f32_16x16x32_f16(af[c], bv, acc, 0, 0, 0);
            }
            if (q == 0)
                F[base0 + r * PD + t2 * 16] = (_Float16)(acc[0] + b0);
        }
    }
}

// ---------------------------------------------------------------------------
// 8 -> 27 conv + L1 normalize via MFMA; ROWS=4, LDS-tiled B input.
// (R5-verified form.)
// ---------------------------------------------------------------------------
__global__ __launch_bounds__(256) void conv8x27n_mfma(const _Float16* __restrict__ HP,
                                                      const _Float16* __restrict__ WF,
                                                      _Float16* __restrict__ WB)
{
    __shared__ _Float16 Wr[32 * 29 * 8];      // 14,848 B
    __shared__ _Float16 T[3 * 6 * 130 * 8];   // 37,440 B: [dz(3)][yy(6)][xs(130)][ch(8)]
    const int tid = threadIdx.x;

    const int b = ((blockIdx.x & 7) << 9) | (blockIdx.x >> 3);  // 4096 blocks
    const int h0 = (b & 31) << 2;
    const int d  = b >> 5;

    for (int i = tid; i < 32 * 29; i += 256) ((half8*)Wr)[i] = ((const half8*)WF)[i];
    // stage tile: rows (d+dz, h0+yy), yy in [0,6), x in [0,130)
    for (int i = tid; i < 3 * 6 * 130; i += 256) {
        const int dz  = i / 780;
        const int rem = i - dz * 780;
        const int yy  = rem / 130;
        const int xs  = rem - yy * 130;
        ((half8*)T)[i] =
            *(const half8*)&HP[((size_t)((d + dz) * PD + (h0 + yy)) * PD + xs) * 8];
    }
    __syncthreads();

    const int lane = tid & 63;
    const int wv   = tid >> 6;
    const int col  = lane & 15;
    const int q    = lane >> 4;

    half8 af[2][7];
    #pragma unroll
    for (int t = 0; t < 2; ++t)
        #pragma unroll
        for (int c = 0; c < 7; ++c)
            af[t][c] = *(const half8*)&Wr[((t * 16 + col) * 29 + (c * 4 + q)) * 8];

    // per-lane LDS base (halves index) for each tap-column c
    int lb[7];
    #pragma unroll
    for (int c = 0; c < 7; ++c) {
        const int tap = min(c * 4 + q, 26);
        const int dz = tap / 9, r9 = tap - dz * 9;
        const int dy = r9 / 3,  dx = r9 - dy * 3;
        lb[c] = ((dz * 6 + dy) * 130 + wv * 32 + col + dx) * 8;
    }

    #pragma unroll
    for (int r = 0; r < 4; ++r) {
        #pragma unroll
        for (int t2 = 0; t2 < 2; ++t2) {
            float4v acc0 = {0.0f, 0.0f, 0.0f, 0.0f};
            float4v acc1 = {0.0f, 0.0f, 0.0f, 0.0f};
            #pragma unroll
            for (int c = 0; c < 7; ++c) {
                const half8 bv = *(const half8*)&T[lb[c] + (r * 130 + t2 * 16) * 8];
                acc0 = __builtin_amdgcn_mfma_f32_16x16x32_f16(af[0][c], bv, acc0, 0, 0, 0);
                acc1 = __builtin_amdgcn_mfma_f32_16x16x32_f16(af[1][c], bv, acc1, 0, 0, 0);
            }

            float s = 0.0f;
            #pragma unroll
            for (int rr = 0; rr < 4; ++rr) {
                s += fabsf(acc0[rr]);
                if (16 + q * 4 + rr < 27) s += fabsf(acc1[rr]);
            }
            s += __shfl_xor(s, 16);
            s += __shfl_xor(s, 32);
            const float rcp = 1.0f / fmaxf(s, 1e-12f);

            const int vox = (d << 14) + ((h0 + r) << 7) + wv * 32 + t2 * 16 + col;
            const size_t base = (size_t)vox * 28;
            half4 o0, o1;
            #pragma unroll
            for (int rr = 0; rr < 4; ++rr) {
                o0[rr] = (_Float16)(acc0[rr] * rcp);
                o1[rr] = (_Float16)(acc1[rr] * rcp);   // pad rows produce 0
            }
            *(half4*)&WB[base + q * 4] = o0;
            if (q < 3)
                *(half4*)&WB[base + 16 + q * 4] = o1;  // q==3: taps 28..31, all pad
        }
    }
}

// ---------------------------------------------------------------------------
// Adaptive stencil, 8ch padded interleaved in/out; ROLLING-Z LDS ring,
// 4 y-rows x 128 x per block (512 threads), 8 z-slices per block.
// 4-slot ring of 6y x 130x x 8ch slices (49,920 B). Per step: stage 1 new
// slice (slot (z+3)&3, disjoint from the 3 read slots), compute, 1 barrier.
// Staging redundancy 1.875x (y 1.5x, z 1.25x). Tap order bit-exact.
// ---------------------------------------------------------------------------
__global__ __launch_bounds__(512) void aconv8i(const _Float16* __restrict__ in,
                                               const _Float16* __restrict__ wb,
                                               _Float16* __restrict__ out)
{
    __shared__ _Float16 T[4][6 * 130 * 8];   // ring: [slot][(yy*130+xs)*8+ch]
    const int b = ((blockIdx.x & 7) << 6) | (blockIdx.x >> 3);  // 512 blocks
    const int h0 = (b & 31) << 2;
    const int d0 = (b >> 5) << 3;            // chunk of 8 z-slices
    const int tid = threadIdx.x;

    // stage input slice z (unpadded plane index, -1..128) into its ring slot
    auto stage = [&](int z) {
        const int slot = (z + 1) & 3;
        for (int i = tid; i < 6 * 130; i += 512) {
            const int yy = i / 130;
            const int xs = i - yy * 130;
            *(half8*)&T[slot][i * 8] =
                *(const half8*)&in[((size_t)((z + 1) * PD + (h0 + yy)) * PD + xs) * 8];
        }
    };

    stage(d0 - 1); stage(d0); stage(d0 + 1);
    __syncthreads();

    const int x  = tid & 127;
    const int ly = tid >> 7;                  // 0..3: which of the 4 y-rows

    for (int z = d0; z < d0 + 8; ++z) {
        if (z <= d0 + 6) stage(z + 2);        // slot (z+3)&3: holds z-2, not read now

        const int idx = (z << 14) + ((h0 + ly) << 7) + x;
        const size_t wbb = (size_t)idx * 28;
        half4 W[7];
        #pragma unroll
        for (int k = 0; k < 7; ++k) W[k] = *(const half4*)(wb + wbb + k * 4);

        half2v a4[4];
        #pragma unroll
        for (int j = 0; j < 4; ++j) a4[j] = half2v{};

        #pragma unroll
        for (int dz = 0; dz < 3; dz++) {
            const int slot = (z + dz) & 3;    // slice z-1+dz
            #pragma unroll
            for (int dy = 0; dy < 3; dy++) {
                const _Float16* rp = &T[slot][((ly + dy) * 130 + (x + 1)) * 8];
                #pragma unroll
                for (int kw = 0; kw < 3; kw++) {
                    const int tap = dz * 9 + dy * 3 + kw;
                    const _Float16 wt = W[tap >> 2][tap & 3];
                    half2v w2; w2[0] = wt; w2[1] = wt;
                    const half8 hv = *(const half8*)(rp + (kw - 1) * 8);
                    const half2v* h2 = (const half2v*)&hv;
                    #pragma unroll
                    for (int j = 0; j < 4; ++j)
                        a4[j] += h2[j] * w2;             // v_pk_fma_f16
                }
            }
        }

        const int s0 = ((z + 1) * PD + (h0 + ly + 1)) * PD + (x + 1);
        half8 o;
        #pragma unroll
        for (int j = 0; j < 4; ++j) { o[2 * j] = a4[j][0]; o[2 * j + 1] = a4[j][1]; }
        *(half8*)&out[(size_t)s0 * 8] = o;

        __syncthreads();   // reads of slot (z)&3 done before next iter overwrites it
    }
}

// ---------------------------------------------------------------------------
// Adaptive stencil, 1ch padded fp16 in; fp32 math. WB stride 28.
// (R3-verified global-read form.)
// TANH=false: padded fp16 out. TANH=true: planar fp32 out (final).
// ---------------------------------------------------------------------------
template<bool TANH>
__global__ __launch_bounds__(256) void aconv1h(const _Float16* __restrict__ in,
                                               const _Float16* __restrict__ wb,
                                               _Float16* __restrict__ outh,
                                               float* __restrict__ outf)
{
    const int b = ((blockIdx.x & 7) << 10) | (blockIdx.x >> 3);
    const int idx = b * 256 + threadIdx.x;
    const int w = idx & 127;
    const int h = (idx >> 7) & 127;
    const int d = idx >> 14;

    const size_t wbb = (size_t)idx * 28;
    half4 W[7];
    #pragma unroll
    for (int k = 0; k < 7; ++k) W[k] = *(const half4*)(wb + wbb + k * 4);

    const int s0 = ((d + 1) * PD + (h + 1)) * PD + (w + 1);

    float acc = 0.0f;
    #pragma unroll
    for (int dz = 0; dz < 3; dz++) {
        #pragma unroll
        for (int dy = 0; dy < 3; dy++) {
            const _Float16* rp = in + s0 + ((dz - 1) * PD + (dy - 1)) * PD;
            #pragma unroll
            for (int kw = 0; kw < 3; kw++) {
                const int tap = dz * 9 + dy * 3 + kw;
                const _Float16 wt = W[tap >> 2][tap & 3];
                acc = fmaf((float)rp[kw - 1], (float)wt, acc);
            }
        }
    }

    if (TANH) outf[idx] = tanhf(acc);
    else      outh[s0] = (_Float16)acc;
}

// ---------------------------------------------------------------------------
// ws layout (~192 MiB): P0 | P1 (33.5 MiB padded 8-ch each) | WB (112 MiB)
//   | F1 | G1 | F2 (4.2 MiB padded 1-ch each) | WF (preformatted weights).
// WF halves: [0]=ac1_w1 [3712]=ac2_w1 [7424]=ac3_w1 [11136]=out_w
//   [14848]=mid_w [18560]=ac1_w2 [25984]=ac2_w2 [33408]=ac3_w2
// ---------------------------------------------------------------------------
extern "C" void kernel_launch(void* const* d_in, const int* in_sizes, int n_in,
                              void* d_out, int out_size, void* d_ws, size_t ws_size,
                              hipStream_t stream)
{
    const float* x      = (const float*)d_in[0];
    const float* ac1_w1 = (const float*)d_in[1];
    const float* ac1_b1 = (const float*)d_in[2];
    const float* ac1_w2 = (const float*)d_in[3];
    const float* ac2_w1 = (const float*)d_in[4];
    const float* ac2_b1 = (const float*)d_in[5];
    const float* ac2_w2 = (const float*)d_in[6];
    const float* ac3_w1 = (const float*)d_in[7];
    const float* ac3_b1 = (const float*)d_in[8];
    const float* ac3_w2 = (const float*)d_in[9];
    const float* mid_w  = (const float*)d_in[10];
    const float* mid_b  = (const float*)d_in[11];
    const float* out_w  = (const float*)d_in[12];
    const float* out_b  = (const float*)d_in[13];
    float* out = (float*)d_out;

    char* ws = (char*)d_ws;
    const size_t PS8 = (size_t)PD * PD * PD * 8 * 2;   // 35,152,000 B
    const size_t PS1 = (size_t)PD * PD * PD * 2;       //  4,394,000 B
    const size_t WBsz = (size_t)VOX * 28 * 2;          // 117,440,512 B
    _Float16* P0 = (_Float16*)(ws);
    _Float16* P1 = (_Float16*)(ws + PS8);
    _Float16* WB = (_Float16*)(ws + 2 * PS8);
    _Float16* F1 = (_Float16*)(ws + 2 * PS8 + WBsz);
    _Float16* G1 = (_Float16*)(ws + 2 * PS8 + WBsz + PS1);
    _Float16* F2 = (_Float16*)(ws + 2 * PS8 + WBsz + 2 * PS1);
    _Float16* WF = (_Float16*)(ws + 2 * PS8 + WBsz + 3 * PS1);
    _Float16* WF8_1  = WF;
    _Float16* WF8_2  = WF + 3712;
    _Float16* WF8_3  = WF + 7424;
    _Float16* WFo    = WF + 11136;
    _Float16* WFmid  = WF + 14848;
    _Float16* WF27_1 = WF + 18560;
    _Float16* WF27_2 = WF + 25984;
    _Float16* WF27_3 = WF + 33408;

    const dim3 blk(256);
    const dim3 blkA(512);
    const dim3 gridT(VOX / 256);               // cast: 8192 blocks
    const dim3 gridM(VOX / 256);               // ROWS=2 MFMA convs: 8192 blocks
    const dim3 gridM4(VOX / 512);              // conv8x27n (ROWS=4): 4096 blocks
    const dim3 gridA(512);                     // rolling-z aconv8i: 512 blocks
    const dim3 gridZ((PD * PD + 255) / 256);   // zero_halo: 67 blocks

    zero_halo<8><<<gridZ, blk, 0, stream>>>(P0);
    zero_halo<8><<<gridZ, blk, 0, stream>>>(P1);
    zero_halo<1><<<gridZ, blk, 0, stream>>>(F1);
    zero_halo<1><<<gridZ, blk, 0, stream>>>(G1);
    zero_halo<1><<<gridZ, blk, 0, stream>>>(F2);
    preformat<<<dim3(8), blk, 0, stream>>>(ac1_w1, ac2_w1, ac3_w1, out_w, mid_w,
                                           ac1_w2, ac2_w2, ac3_w2, WF);

    // ---- block 1 ----
    cast_hp<<<gridT, blk, 0, stream>>>(x, P0);                       // X16 = P0
    conv8x8_mfma<true ><<<gridM, blk, 0, stream>>>(P0, WF8_1, ac1_b1, P1);   // H1
    conv8x27n_mfma<<<gridM4, blk, 0, stream>>>(P1, WF27_1, WB);
    aconv8i<<<gridA, blkA, 0, stream>>>(P0, WB, P1);                 // (H1 dead)
    aconv8i<<<gridA, blkA, 0, stream>>>(P1, WB, P0);
    aconv8i<<<gridA, blkA, 0, stream>>>(P0, WB, P1);                 // C1 = P1
    // ---- mid conv ----
    conv8x8_mfma<false><<<gridM, blk, 0, stream>>>(P1, WFmid, mid_b, P0);    // M = P0
    // ---- block 2 ----
    conv8x8_mfma<true ><<<gridM, blk, 0, stream>>>(P0, WF8_2, ac2_b1, P1);   // H2
    conv8x27n_mfma<<<gridM4, blk, 0, stream>>>(P1, WF27_2, WB);
    aconv8i<<<gridA, blkA, 0, stream>>>(P0, WB, P1);
    aconv8i<<<gridA, blkA, 0, stream>>>(P1, WB, P0);
    aconv8i<<<gridA, blkA, 0, stream>>>(P0, WB, P1);                 // mid2 = P1
    // ---- block 3 (weights from mid2 = P1) ----
    conv8x8_mfma<true ><<<gridM, blk, 0, stream>>>(P1, WF8_3, ac3_b1, P0);   // H3
    conv8x27n_mfma<<<gridM4, blk, 0, stream>>>(P0, WF27_3, WB);
    conv8x1_mfma<<<gridM, blk, 0, stream>>>(P1, WFo, out_b, F1);
    aconv1h<false><<<gridT, blk, 0, stream>>>(F1, WB, G1, nullptr);
    aconv1h<false><<<gridT, blk, 0, stream>>>(G1, WB, F2, nullptr);
    aconv1h<true ><<<gridT, blk, 0, stream>>>(F2, WB, nullptr, out);
}

// Round 9
// 711.542 us; speedup vs baseline: 1.0818x; 1.0190x over previous
//
#include <hip/hip_runtime.h>
#include <math.h>

#define DSZ 128
#define VOX (DSZ*DSZ*DSZ)  // 2,097,152 voxels
#define PD  130            // padded dim (halo 1 on all 6 faces)

typedef _Float16 half8 __attribute__((ext_vector_type(8)));
typedef _Float16 half4 __attribute__((ext_vector_type(4)));
typedef _Float16 half2v __attribute__((ext_vector_type(2)));
typedef float float4v __attribute__((ext_vector_type(4)));

// Halo-padded tensors: slot(z,y,x) = ((z+1)*130 + (y+1))*130 + (x+1),
// z,y,x in [-1,128]. 8-ch interleaved: halves = slot*8 (33.5 MiB).
// 1-ch: halves = slot (4.2 MiB). Halos zeroed once; interior-only writes.
// WB: interleaved [vox][28] halves (27 taps + 1 pad), 112 MiB.

// ---------------------------------------------------------------------------
// Zero the halo of a padded tensor (ws is re-poisoned before every call).
// ---------------------------------------------------------------------------
template<int CH>
__global__ __launch_bounds__(256) void zero_halo(_Float16* __restrict__ P)
{
    const int t = blockIdx.x * 256 + threadIdx.x;   // (zp,yp) row in [0,130)^2
    if (t >= PD * PD) return;
    const int zp = t / PD;
    const int yp = t - zp * PD;
    _Float16* row = P + (size_t)t * PD * CH;
    if (zp == 0 || zp == PD - 1 || yp == 0 || yp == PD - 1) {
        if (CH == 8) {
            half8 zz = {};
            for (int x = 0; x < PD; ++x) *(half8*)&row[x * 8] = zz;
        } else {
            for (int x = 0; x < PD; ++x) row[x] = (_Float16)0.0f;
        }
    } else {
        if (CH == 8) {
            half8 zz = {};
            *(half8*)&row[0] = zz;
            *(half8*)&row[(PD - 1) * 8] = zz;
        } else {
            row[0] = (_Float16)0.0f;
            row[PD - 1] = (_Float16)0.0f;
        }
    }
}

// ---------------------------------------------------------------------------
// Preformat conv weights -> fp16 [oc][tap(stride 29)][ic], once per launch.
// Blocks: 0..2 = ac{1,2,3}_w1; 3 = out_w; 4 = mid_w; 5..7 = ac{1,2,3}_w2.
// ---------------------------------------------------------------------------
__global__ __launch_bounds__(256) void preformat(const float* __restrict__ w1a, const float* __restrict__ w1b,
                                                 const float* __restrict__ w1c, const float* __restrict__ outw,
                                                 const float* __restrict__ midw,
                                                 const float* __restrict__ w2a, const float* __restrict__ w2b,
                                                 const float* __restrict__ w2c, _Float16* __restrict__ WF)
{
    const int bid = blockIdx.x, tid = threadIdx.x;
    const float* src;
    _Float16* dst;
    int nelem, sz;
    if (bid < 3)       { src = bid == 0 ? w1a : bid == 1 ? w1b : w1c; dst = WF + bid * 3712; nelem = 8 * 216; sz = 16 * 29; }
    else if (bid == 3) { src = outw; dst = WF + 3 * 3712; nelem = 216;     sz = 16 * 29; }
    else if (bid == 4) { src = midw; dst = WF + 4 * 3712; nelem = 8 * 216; sz = 16 * 29; }
    else               { src = bid == 5 ? w2a : bid == 6 ? w2b : w2c; dst = WF + 5 * 3712 + (bid - 5) * 7424; nelem = 27 * 216; sz = 32 * 29; }
    for (int i = tid; i < sz; i += 256) ((half8*)dst)[i] = half8{};
    __syncthreads();
    for (int i = tid; i < nelem; i += 256) {
        const int oc = i / 216;
        const int rem = i - oc * 216;
        const int ic = rem / 27;
        const int tap = rem - ic * 27;
        dst[(oc * 29 + tap) * 8 + ic] = (_Float16)src[i];
    }
}

// ---------------------------------------------------------------------------
// Cast planar fp32 (8ch) -> halo-padded interleaved fp16 (interior only).
// ---------------------------------------------------------------------------
__global__ __launch_bounds__(256) void cast_hp(const float* __restrict__ in,
                                               _Float16* __restrict__ hp)
{
    const int idx = blockIdx.x * 256 + threadIdx.x;
    const int w = idx & 127;
    const int h = (idx >> 7) & 127;
    const int d = idx >> 14;
    half8 v;
    #pragma unroll
    for (int ic = 0; ic < 8; ++ic) v[ic] = (_Float16)in[(size_t)ic * VOX + idx];
    const int slot = ((d + 1) * PD + (h + 1)) * PD + (w + 1);
    *(half8*)&hp[(size_t)slot * 8] = v;
}

// ---------------------------------------------------------------------------
// Dense 3x3x3 conv 8->8 (+bias, opt relu) via MFMA; padded in/out, ROWS=2.
// ---------------------------------------------------------------------------
template<bool RELU>
__global__ __launch_bounds__(256) void conv8x8_mfma(const _Float16* __restrict__ DP,
                                                    const _Float16* __restrict__ WF,
                                                    const float* __restrict__ bias,
                                                    _Float16* __restrict__ HO)
{
    __shared__ _Float16 Wr[16 * 29 * 8];
    const int tid = threadIdx.x;
    for (int i = tid; i < 16 * 29; i += 256) ((half8*)Wr)[i] = ((const half8*)WF)[i];
    __syncthreads();

    const int b = ((blockIdx.x & 7) << 10) | (blockIdx.x >> 3);  // 8192 blocks
    const int h0 = (b & 63) << 1;
    const int d  = b >> 6;
    const int lane = tid & 63;
    const int wv   = tid >> 6;
    const int col  = lane & 15;
    const int q    = lane >> 4;

    half8 af[7];
    #pragma unroll
    for (int c = 0; c < 7; ++c)
        af[c] = *(const half8*)&Wr[(col * 29 + (c * 4 + q)) * 8];

    const int base0 = ((d + 1) * PD + (h0 + 1)) * PD + 1 + wv * 32 + col;
    const _Float16* p[7];
    #pragma unroll
    for (int c = 0; c < 7; ++c) {
        const int tap = min(c * 4 + q, 26);
        const int dz = tap / 9, r9 = tap - dz * 9;
        const int dy = r9 / 3,  dx = r9 - dy * 3;
        p[c] = DP + (size_t)(base0 + ((dz - 1) * PD + (dy - 1)) * PD + (dx - 1)) * 8;
    }

    #pragma unroll
    for (int r = 0; r < 2; ++r) {
        #pragma unroll
        for (int t2 = 0; t2 < 2; ++t2) {
            float4v acc = {0.0f, 0.0f, 0.0f, 0.0f};
            #pragma unroll
            for (int c = 0; c < 7; ++c) {
                const half8 bv = *(const half8*)(p[c] + (r * PD + t2 * 16) * 8);
                acc = __builtin_amdgcn_mfma_f32_16x16x32_f16(af[c], bv, acc, 0, 0, 0);
            }
            if (q < 2) {
                const float4v bl = ((const float4v*)bias)[q];
                half4 hv;
                #pragma unroll
                for (int rr = 0; rr < 4; ++rr) {
                    float v = acc[rr] + bl[rr];
                    if (RELU) v = fmaxf(v, 0.0f);
                    hv[rr] = (_Float16)v;
                }
                *(half4*)&HO[(size_t)(base0 + r * PD + t2 * 16) * 8 + q * 4] = hv;
            }
        }
    }
}

// ---------------------------------------------------------------------------
// Dense 3x3x3 conv 8->1 (+bias) via MFMA; padded in -> padded 1-ch fp16 out.
// ---------------------------------------------------------------------------
__global__ __launch_bounds__(256) void conv8x1_mfma(const _Float16* __restrict__ DP,
                                                    const _Float16* __restrict__ WF,
                                                    const float* __restrict__ bias,
                                                    _Float16* __restrict__ F)
{
    __shared__ _Float16 Wr[16 * 29 * 8];
    const int tid = threadIdx.x;
    for (int i = tid; i < 16 * 29; i += 256) ((half8*)Wr)[i] = ((const half8*)WF)[i];
    __syncthreads();

    const int b = ((blockIdx.x & 7) << 10) | (blockIdx.x >> 3);  // 8192 blocks
    const int h0 = (b & 63) << 1;
    const int d  = b >> 6;
    const int lane = tid & 63;
    const int wv   = tid >> 6;
    const int col  = lane & 15;
    const int q    = lane >> 4;

    half8 af[7];
    #pragma unroll
    for (int c = 0; c < 7; ++c)
        af[c] = *(const half8*)&Wr[(col * 29 + (c * 4 + q)) * 8];

    const int base0 = ((d + 1) * PD + (h0 + 1)) * PD + 1 + wv * 32 + col;
    const _Float16* p[7];
    #pragma unroll
    for (int c = 0; c < 7; ++c) {
        const int tap = min(c * 4 + q, 26);
        const int dz = tap / 9, r9 = tap - dz * 9;
        const int dy = r9 / 3,  dx = r9 - dy * 3;
        p[c] = DP + (size_t)(base0 + ((dz - 1) * PD + (dy - 1)) * PD + (dx - 1)) * 8;
    }

    const float b0 = bias[0];
    #pragma unroll
    for (int r = 0; r < 2; ++r) {
        #pragma unroll
        for (int t2 = 0; t2 < 2; ++t2) {
            float4v acc = {0.0f, 0.0f, 0.0f, 0.0f};
            #pragma unroll
            for (int c = 0; c < 7; ++c) {
                const half8 bv = *(const half8*)(p[c] + (r * PD + t2 * 16) * 8);
                acc = __builtin_amdgcn_mfma_f32_16x16x32_f16(af[c], bv, acc, 0, 0, 0);
            }
            if (q == 0)
                F[base0 + r * PD + t2 * 16] = (_Float16)(acc[0] + b0);
        }
    }
}

// ---------------------------------------------------------------------------
// 8 -> 27 conv + L1 normalize via MFMA; ROWS=4, LDS-tiled B input.
// Weights read DIRECTLY from global WF (7.4 KB, L1/L2-resident) — no Wr LDS.
// LDS = 37,440 B tile only -> 4 blocks/CU (vs 2-3 with Wr staged).
// q==3 hi half4 covers taps 28..31 — all pad, store skipped.
// ---------------------------------------------------------------------------
__global__ __launch_bounds__(256) void conv8x27n_mfma(const _Float16* __restrict__ HP,
                                                      const _Float16* __restrict__ WF,
                                                      _Float16* __restrict__ WB)
{
    __shared__ _Float16 T[3 * 6 * 130 * 8];   // 37,440 B: [dz(3)][yy(6)][xs(130)][ch(8)]
    const int tid = threadIdx.x;

    const int b = ((blockIdx.x & 7) << 9) | (blockIdx.x >> 3);  // 4096 blocks
    const int h0 = (b & 31) << 2;
    const int d  = b >> 5;

    // stage tile: rows (d+dz, h0+yy), yy in [0,6), x in [0,130)
    for (int i = tid; i < 3 * 6 * 130; i += 256) {
        const int dz  = i / 780;
        const int rem = i - dz * 780;
        const int yy  = rem / 130;
        const int xs  = rem - yy * 130;
        ((half8*)T)[i] =
            *(const half8*)&HP[((size_t)((d + dz) * PD + (h0 + yy)) * PD + xs) * 8];
    }

    const int lane = tid & 63;
    const int wv   = tid >> 6;
    const int col  = lane & 15;
    const int q    = lane >> 4;

    // weight fragments straight from global (latency hides under staging)
    half8 af[2][7];
    #pragma unroll
    for (int t = 0; t < 2; ++t)
        #pragma unroll
        for (int c = 0; c < 7; ++c)
            af[t][c] = *(const half8*)&WF[((t * 16 + col) * 29 + (c * 4 + q)) * 8];

    // per-lane LDS base (halves index) for each tap-column c
    int lb[7];
    #pragma unroll
    for (int c = 0; c < 7; ++c) {
        const int tap = min(c * 4 + q, 26);
        const int dz = tap / 9, r9 = tap - dz * 9;
        const int dy = r9 / 3,  dx = r9 - dy * 3;
        lb[c] = ((dz * 6 + dy) * 130 + wv * 32 + col + dx) * 8;
    }

    __syncthreads();

    #pragma unroll
    for (int r = 0; r < 4; ++r) {
        #pragma unroll
        for (int t2 = 0; t2 < 2; ++t2) {
            float4v acc0 = {0.0f, 0.0f, 0.0f, 0.0f};
            float4v acc1 = {0.0f, 0.0f, 0.0f, 0.0f};
            #pragma unroll
            for (int c = 0; c < 7; ++c) {
                const half8 bv = *(const half8*)&T[lb[c] + (r * 130 + t2 * 16) * 8];
                acc0 = __builtin_amdgcn_mfma_f32_16x16x32_f16(af[0][c], bv, acc0, 0, 0, 0);
                acc1 = __builtin_amdgcn_mfma_f32_16x16x32_f16(af[1][c], bv, acc1, 0, 0, 0);
            }

            float s = 0.0f;
            #pragma unroll
            for (int rr = 0; rr < 4; ++rr) {
                s += fabsf(acc0[rr]);
                if (16 + q * 4 + rr < 27) s += fabsf(acc1[rr]);
            }
            s += __shfl_xor(s, 16);
            s += __shfl_xor(s, 32);
            const float rcp = 1.0f / fmaxf(s, 1e-12f);

            const int vox = (d << 14) + ((h0 + r) << 7) + wv * 32 + t2 * 16 + col;
            const size_t base = (size_t)vox * 28;
            half4 o0, o1;
            #pragma unroll
            for (int rr = 0; rr < 4; ++rr) {
                o0[rr] = (_Float16)(acc0[rr] * rcp);
                o1[rr] = (_Float16)(acc1[rr] * rcp);   // pad rows produce 0
            }
            *(half4*)&WB[base + q * 4] = o0;
            if (q < 3)
                *(half4*)&WB[base + 16 + q * 4] = o1;  // q==3: taps 28..31, all pad
        }
    }
}

// ---------------------------------------------------------------------------
// Adaptive stencil, 8ch padded interleaved in/out; ROLLING-Z LDS ring,
// 4 y-rows x 128 x per block (512 threads), 8 z-slices per block.
// (R7-verified form.)
// ---------------------------------------------------------------------------
__global__ __launch_bounds__(512) void aconv8i(const _Float16* __restrict__ in,
                                               const _Float16* __restrict__ wb,
                                               _Float16* __restrict__ out)
{
    __shared__ _Float16 T[4][6 * 130 * 8];   // ring: [slot][(yy*130+xs)*8+ch]
    const int b = ((blockIdx.x & 7) << 6) | (blockIdx.x >> 3);  // 512 blocks
    const int h0 = (b & 31) << 2;
    const int d0 = (b >> 5) << 3;            // chunk of 8 z-slices
    const int tid = threadIdx.x;

    // stage input slice z (unpadded plane index, -1..128) into its ring slot
    auto stage = [&](int z) {
        const int slot = (z + 1) & 3;
        for (int i = tid; i < 6 * 130; i += 512) {
            const int yy = i / 130;
            const int xs = i - yy * 130;
            *(half8*)&T[slot][i * 8] =
                *(const half8*)&in[((size_t)((z + 1) * PD + (h0 + yy)) * PD + xs) * 8];
        }
    };

    stage(d0 - 1); stage(d0); stage(d0 + 1);
    __syncthreads();

    const int x  = tid & 127;
    const int ly = tid >> 7;                  // 0..3: which of the 4 y-rows

    for (int z = d0; z < d0 + 8; ++z) {
        if (z <= d0 + 6) stage(z + 2);        // slot (z+3)&3: holds z-2, not read now

        const int idx = (z << 14) + ((h0 + ly) << 7) + x;
        const size_t wbb = (size_t)idx * 28;
        half4 W[7];
        #pragma unroll
        for (int k = 0; k < 7; ++k) W[k] = *(const half4*)(wb + wbb + k * 4);

        half2v a4[4];
        #pragma unroll
        for (int j = 0; j < 4; ++j) a4[j] = half2v{};

        #pragma unroll
        for (int dz = 0; dz < 3; dz++) {
            const int slot = (z + dz) & 3;    // slice z-1+dz
            #pragma unroll
            for (int dy = 0; dy < 3; dy++) {
                const _Float16* rp = &T[slot][((ly + dy) * 130 + (x + 1)) * 8];
                #pragma unroll
                for (int kw = 0; kw < 3; kw++) {
                    const int tap = dz * 9 + dy * 3 + kw;
                    const _Float16 wt = W[tap >> 2][tap & 3];
                    half2v w2; w2[0] = wt; w2[1] = wt;
                    const half8 hv = *(const half8*)(rp + (kw - 1) * 8);
                    const half2v* h2 = (const half2v*)&hv;
                    #pragma unroll
                    for (int j = 0; j < 4; ++j)
                        a4[j] += h2[j] * w2;             // v_pk_fma_f16
                }
            }
        }

        const int s0 = ((z + 1) * PD + (h0 + ly + 1)) * PD + (x + 1);
        half8 o;
        #pragma unroll
        for (int j = 0; j < 4; ++j) { o[2 * j] = a4[j][0]; o[2 * j + 1] = a4[j][1]; }
        *(half8*)&out[(size_t)s0 * 8] = o;

        __syncthreads();   // reads of slot (z)&3 done before next iter overwrites it
    }
}

// ---------------------------------------------------------------------------
// Adaptive stencil, 1ch padded fp16 in; fp32 math. WB stride 28.
// (R3-verified global-read form.)
// TANH=false: padded fp16 out. TANH=true: planar fp32 out (final).
// ---------------------------------------------------------------------------
template<bool TANH>
__global__ __launch_bounds__(256) void aconv1h(const _Float16* __restrict__ in,
                                               const _Float16* __restrict__ wb,
                                               _Float16* __restrict__ outh,
                                               float* __restrict__ outf)
{
    const int b = ((blockIdx.x & 7) << 10) | (blockIdx.x >> 3);
    const int idx = b * 256 + threadIdx.x;
    const int w = idx & 127;
    const int h = (idx >> 7) & 127;
    const int d = idx >> 14;

    const size_t wbb = (size_t)idx * 28;
    half4 W[7];
    #pragma unroll
    for (int k = 0; k < 7; ++k) W[k] = *(const half4*)(wb + wbb + k * 4);

    const int s0 = ((d + 1) * PD + (h + 1)) * PD + (w + 1);

    float acc = 0.0f;
    #pragma unroll
    for (int dz = 0; dz < 3; dz++) {
        #pragma unroll
        for (int dy = 0; dy < 3; dy++) {
            const _Float16* rp = in + s0 + ((dz - 1) * PD + (dy - 1)) * PD;
            #pragma unroll
            for (int kw = 0; kw < 3; kw++) {
                const int tap = dz * 9 + dy * 3 + kw;
                const _Float16 wt = W[tap >> 2][tap & 3];
                acc = fmaf((float)rp[kw - 1], (float)wt, acc);
            }
        }
    }

    if (TANH) outf[idx] = tanhf(acc);
    else      outh[s0] = (_Float16)acc;
}

// ---------------------------------------------------------------------------
// ws layout (~192 MiB): P0 | P1 (33.5 MiB padded 8-ch each) | WB (112 MiB)
//   | F1 | G1 | F2 (4.2 MiB padded 1-ch each) | WF (preformatted weights).
// WF halves: [0]=ac1_w1 [3712]=ac2_w1 [7424]=ac3_w1 [11136]=out_w
//   [14848]=mid_w [18560]=ac1_w2 [25984]=ac2_w2 [33408]=ac3_w2
// ---------------------------------------------------------------------------
extern "C" void kernel_launch(void* const* d_in, const int* in_sizes, int n_in,
                              void* d_out, int out_size, void* d_ws, size_t ws_size,
                              hipStream_t stream)
{
    const float* x      = (const float*)d_in[0];
    const float* ac1_w1 = (const float*)d_in[1];
    const float* ac1_b1 = (const float*)d_in[2];
    const float* ac1_w2 = (const float*)d_in[3];
    const float* ac2_w1 = (const float*)d_in[4];
    const float* ac2_b1 = (const float*)d_in[5];
    const float* ac2_w2 = (const float*)d_in[6];
    const float* ac3_w1 = (const float*)d_in[7];
    const float* ac3_b1 = (const float*)d_in[8];
    const float* ac3_w2 = (const float*)d_in[9];
    const float* mid_w  = (const float*)d_in[10];
    const float* mid_b  = (const float*)d_in[11];
    const float* out_w  = (const float*)d_in[12];
    const float* out_b  = (const float*)d_in[13];
    float* out = (float*)d_out;

    char* ws = (char*)d_ws;
    const size_t PS8 = (size_t)PD * PD * PD * 8 * 2;   // 35,152,000 B
    const size_t PS1 = (size_t)PD * PD * PD * 2;       //  4,394,000 B
    const size_t WBsz = (size_t)VOX * 28 * 2;          // 117,440,512 B
    _Float16* P0 = (_Float16*)(ws);
    _Float16* P1 = (_Float16*)(ws + PS8);
    _Float16* WB = (_Float16*)(ws + 2 * PS8);
    _Float16* F1 = (_Float16*)(ws + 2 * PS8 + WBsz);
    _Float16* G1 = (_Float16*)(ws + 2 * PS8 + WBsz + PS1);
    _Float16* F2 = (_Float16*)(ws + 2 * PS8 + WBsz + 2 * PS1);
    _Float16* WF = (_Float16*)(ws + 2 * PS8 + WBsz + 3 * PS1);
    _Float16* WF8_1  = WF;
    _Float16* WF8_2  = WF + 3712;
    _Float16* WF8_3  = WF + 7424;
    _Float16* WFo    = WF + 11136;
    _Float16* WFmid  = WF + 14848;
    _Float16* WF27_1 = WF + 18560;
    _Float16* WF27_2 = WF + 25984;
    _Float16* WF27_3 = WF + 33408;

    const dim3 blk(256);
    const dim3 blkA(512);
    const dim3 gridT(VOX / 256);               // cast: 8192 blocks
    const dim3 gridM(VOX / 256);               // ROWS=2 MFMA convs: 8192 blocks
    const dim3 gridM4(VOX / 512);              // conv8x27n (ROWS=4): 4096 blocks
    const dim3 gridA(512);                     // rolling-z aconv8i: 512 blocks
    const dim3 gridZ((PD * PD + 255) / 256);   // zero_halo: 67 blocks

    zero_halo<8><<<gridZ, blk, 0, stream>>>(P0);
    zero_halo<8><<<gridZ, blk, 0, stream>>>(P1);
    zero_halo<1><<<gridZ, blk, 0, stream>>>(F1);
    zero_halo<1><<<gridZ, blk, 0, stream>>>(G1);
    zero_halo<1><<<gridZ, blk, 0, stream>>>(F2);
    preformat<<<dim3(8), blk, 0, stream>>>(ac1_w1, ac2_w1, ac3_w1, out_w, mid_w,
                                           ac1_w2, ac2_w2, ac3_w2, WF);

    // ---- block 1 ----
    cast_hp<<<gridT, blk, 0, stream>>>(x, P0);                       // X16 = P0
    conv8x8_mfma<true ><<<gridM, blk, 0, stream>>>(P0, WF8_1, ac1_b1, P1);   // H1
    conv8x27n_mfma<<<gridM4, blk, 0, stream>>>(P1, WF27_1, WB);
    aconv8i<<<gridA, blkA, 0, stream>>>(P0, WB, P1);                 // (H1 dead)
    aconv8i<<<gridA, blkA, 0, stream>>>(P1, WB, P0);
    aconv8i<<<gridA, blkA, 0, stream>>>(P0, WB, P1);                 // C1 = P1
    // ---- mid conv ----
    conv8x8_mfma<false><<<gridM, blk, 0, stream>>>(P1, WFmid, mid_b, P0);    // M = P0
    // ---- block 2 ----
    conv8x8_mfma<true ><<<gridM, blk, 0, stream>>>(P0, WF8_2, ac2_b1, P1);   // H2
    conv8x27n_mfma<<<gridM4, blk, 0, stream>>>(P1, WF27_2, WB);
    aconv8i<<<gridA, blkA, 0, stream>>>(P0, WB, P1);
    aconv8i<<<gridA, blkA, 0, stream>>>(P1, WB, P0);
    aconv8i<<<gridA, blkA, 0, stream>>>(P0, WB, P1);                 // mid2 = P1
    // ---- block 3 (weights from mid2 = P1) ----
    conv8x8_mfma<true ><<<gridM, blk, 0, stream>>>(P1, WF8_3, ac3_b1, P0);   // H3
    conv8x27n_mfma<<<gridM4, blk, 0, stream>>>(P0, WF27_3, WB);
    conv8x1_mfma<<<gridM, blk, 0, stream>>>(P1, WFo, out_b, F1);
    aconv1h<false><<<gridT, blk, 0, stream>>>(F1, WB, G1, nullptr);
    aconv1h<false><<<gridT, blk, 0, stream>>>(G1, WB, F2, nullptr);
    aconv1h<true ><<<gridT, blk, 0, stream>>>(F2, WB, nullptr, out);
}

// Round 10
// 708.571 us; speedup vs baseline: 1.0863x; 1.0042x over previous
//
#include <hip/hip_runtime.h>
#include <math.h>

#define DSZ 128
#define VOX (DSZ*DSZ*DSZ)  // 2,097,152 voxels
#define PD  130            // padded dim (halo 1 on all 6 faces)

typedef _Float16 half8 __attribute__((ext_vector_type(8)));
typedef _Float16 half4 __attribute__((ext_vector_type(4)));
typedef _Float16 half2v __attribute__((ext_vector_type(2)));
typedef float float4v __attribute__((ext_vector_type(4)));

// Halo-padded tensors: slot(z,y,x) = ((z+1)*130 + (y+1))*130 + (x+1),
// z,y,x in [-1,128]. 8-ch interleaved: halves = slot*8 (33.5 MiB).
// 1-ch: halves = slot (4.2 MiB). Halos zeroed once; interior-only writes.
// WB grouped-planar: [group(7)][vox][4] halves; tap t = (t>>2)*VOX*4 + vox*4
// + (t&3). 117.4 MiB. Group 6 j=3 (tap 27) is pad, never read.
// Coalescing: producer stores 128B runs; consumer half4 loads 512B/wave.

// ---------------------------------------------------------------------------
// Zero the halo of a padded tensor (ws is re-poisoned before every call).
// ---------------------------------------------------------------------------
template<int CH>
__global__ __launch_bounds__(256) void zero_halo(_Float16* __restrict__ P)
{
    const int t = blockIdx.x * 256 + threadIdx.x;   // (zp,yp) row in [0,130)^2
    if (t >= PD * PD) return;
    const int zp = t / PD;
    const int yp = t - zp * PD;
    _Float16* row = P + (size_t)t * PD * CH;
    if (zp == 0 || zp == PD - 1 || yp == 0 || yp == PD - 1) {
        if (CH == 8) {
            half8 zz = {};
            for (int x = 0; x < PD; ++x) *(half8*)&row[x * 8] = zz;
        } else {
            for (int x = 0; x < PD; ++x) row[x] = (_Float16)0.0f;
        }
    } else {
        if (CH == 8) {
            half8 zz = {};
            *(half8*)&row[0] = zz;
            *(half8*)&row[(PD - 1) * 8] = zz;
        } else {
            row[0] = (_Float16)0.0f;
            row[PD - 1] = (_Float16)0.0f;
        }
    }
}

// ---------------------------------------------------------------------------
// Preformat conv weights -> fp16 [oc][tap(stride 29)][ic], once per launch.
// Blocks: 0..2 = ac{1,2,3}_w1; 3 = out_w; 4 = mid_w; 5..7 = ac{1,2,3}_w2.
// ---------------------------------------------------------------------------
__global__ __launch_bounds__(256) void preformat(const float* __restrict__ w1a, const float* __restrict__ w1b,
                                                 const float* __restrict__ w1c, const float* __restrict__ outw,
                                                 const float* __restrict__ midw,
                                                 const float* __restrict__ w2a, const float* __restrict__ w2b,
                                                 const float* __restrict__ w2c, _Float16* __restrict__ WF)
{
    const int bid = blockIdx.x, tid = threadIdx.x;
    const float* src;
    _Float16* dst;
    int nelem, sz;
    if (bid < 3)       { src = bid == 0 ? w1a : bid == 1 ? w1b : w1c; dst = WF + bid * 3712; nelem = 8 * 216; sz = 16 * 29; }
    else if (bid == 3) { src = outw; dst = WF + 3 * 3712; nelem = 216;     sz = 16 * 29; }
    else if (bid == 4) { src = midw; dst = WF + 4 * 3712; nelem = 8 * 216; sz = 16 * 29; }
    else               { src = bid == 5 ? w2a : bid == 6 ? w2b : w2c; dst = WF + 5 * 3712 + (bid - 5) * 7424; nelem = 27 * 216; sz = 32 * 29; }
    for (int i = tid; i < sz; i += 256) ((half8*)dst)[i] = half8{};
    __syncthreads();
    for (int i = tid; i < nelem; i += 256) {
        const int oc = i / 216;
        const int rem = i - oc * 216;
        const int ic = rem / 27;
        const int tap = rem - ic * 27;
        dst[(oc * 29 + tap) * 8 + ic] = (_Float16)src[i];
    }
}

// ---------------------------------------------------------------------------
// Cast planar fp32 (8ch) -> halo-padded interleaved fp16 (interior only).
// ---------------------------------------------------------------------------
__global__ __launch_bounds__(256) void cast_hp(const float* __restrict__ in,
                                               _Float16* __restrict__ hp)
{
    const int idx = blockIdx.x * 256 + threadIdx.x;
    const int w = idx & 127;
    const int h = (idx >> 7) & 127;
    const int d = idx >> 14;
    half8 v;
    #pragma unroll
    for (int ic = 0; ic < 8; ++ic) v[ic] = (_Float16)in[(size_t)ic * VOX + idx];
    const int slot = ((d + 1) * PD + (h + 1)) * PD + (w + 1);
    *(half8*)&hp[(size_t)slot * 8] = v;
}

// ---------------------------------------------------------------------------
// Dense 3x3x3 conv 8->8 (+bias, opt relu) via MFMA; padded in/out, ROWS=2.
// ---------------------------------------------------------------------------
template<bool RELU>
__global__ __launch_bounds__(256) void conv8x8_mfma(const _Float16* __restrict__ DP,
                                                    const _Float16* __restrict__ WF,
                                                    const float* __restrict__ bias,
                                                    _Float16* __restrict__ HO)
{
    __shared__ _Float16 Wr[16 * 29 * 8];
    const int tid = threadIdx.x;
    for (int i = tid; i < 16 * 29; i += 256) ((half8*)Wr)[i] = ((const half8*)WF)[i];
    __syncthreads();

    const int b = ((blockIdx.x & 7) << 10) | (blockIdx.x >> 3);  // 8192 blocks
    const int h0 = (b & 63) << 1;
    const int d  = b >> 6;
    const int lane = tid & 63;
    const int wv   = tid >> 6;
    const int col  = lane & 15;
    const int q    = lane >> 4;

    half8 af[7];
    #pragma unroll
    for (int c = 0; c < 7; ++c)
        af[c] = *(const half8*)&Wr[(col * 29 + (c * 4 + q)) * 8];

    const int base0 = ((d + 1) * PD + (h0 + 1)) * PD + 1 + wv * 32 + col;
    const _Float16* p[7];
    #pragma unroll
    for (int c = 0; c < 7; ++c) {
        const int tap = min(c * 4 + q, 26);
        const int dz = tap / 9, r9 = tap - dz * 9;
        const int dy = r9 / 3,  dx = r9 - dy * 3;
        p[c] = DP + (size_t)(base0 + ((dz - 1) * PD + (dy - 1)) * PD + (dx - 1)) * 8;
    }

    #pragma unroll
    for (int r = 0; r < 2; ++r) {
        #pragma unroll
        for (int t2 = 0; t2 < 2; ++t2) {
            float4v acc = {0.0f, 0.0f, 0.0f, 0.0f};
            #pragma unroll
            for (int c = 0; c < 7; ++c) {
                const half8 bv = *(const half8*)(p[c] + (r * PD + t2 * 16) * 8);
                acc = __builtin_amdgcn_mfma_f32_16x16x32_f16(af[c], bv, acc, 0, 0, 0);
            }
            if (q < 2) {
                const float4v bl = ((const float4v*)bias)[q];
                half4 hv;
                #pragma unroll
                for (int rr = 0; rr < 4; ++rr) {
                    float v = acc[rr] + bl[rr];
                    if (RELU) v = fmaxf(v, 0.0f);
                    hv[rr] = (_Float16)v;
                }
                *(half4*)&HO[(size_t)(base0 + r * PD + t2 * 16) * 8 + q * 4] = hv;
            }
        }
    }
}

// ---------------------------------------------------------------------------
// Dense 3x3x3 conv 8->1 (+bias) via MFMA; padded in -> padded 1-ch fp16 out.
// ---------------------------------------------------------------------------
__global__ __launch_bounds__(256) void conv8x1_mfma(const _Float16* __restrict__ DP,
                                                    const _Float16* __restrict__ WF,
                                                    const float* __restrict__ bias,
                                                    _Float16* __restrict__ F)
{
    __shared__ _Float16 Wr[16 * 29 * 8];
    const int tid = threadIdx.x;
    for (int i = tid; i < 16 * 29; i += 256) ((half8*)Wr)[i] = ((const half8*)WF)[i];
    __syncthreads();

    const int b = ((blockIdx.x & 7) << 10) | (blockIdx.x >> 3);  // 8192 blocks
    const int h0 = (b & 63) << 1;
    const int d  = b >> 6;
    const int lane = tid & 63;
    const int wv   = tid >> 6;
    const int col  = lane & 15;
    const int q    = lane >> 4;

    half8 af[7];
    #pragma unroll
    for (int c = 0; c < 7; ++c)
        af[c] = *(const half8*)&Wr[(col * 29 + (c * 4 + q)) * 8];

    const int base0 = ((d + 1) * PD + (h0 + 1)) * PD + 1 + wv * 32 + col;
    const _Float16* p[7];
    #pragma unroll
    for (int c = 0; c < 7; ++c) {
        const int tap = min(c * 4 + q, 26);
        const int dz = tap / 9, r9 = tap - dz * 9;
        const int dy = r9 / 3,  dx = r9 - dy * 3;
        p[c] = DP + (size_t)(base0 + ((dz - 1) * PD + (dy - 1)) * PD + (dx - 1)) * 8;
    }

    const float b0 = bias[0];
    #pragma unroll
    for (int r = 0; r < 2; ++r) {
        #pragma unroll
        for (int t2 = 0; t2 < 2; ++t2) {
            float4v acc = {0.0f, 0.0f, 0.0f, 0.0f};
            #pragma unroll
            for (int c = 0; c < 7; ++c) {
                const half8 bv = *(const half8*)(p[c] + (r * PD + t2 * 16) * 8);
                acc = __builtin_amdgcn_mfma_f32_16x16x32_f16(af[c], bv, acc, 0, 0, 0);
            }
            if (q == 0)
                F[base0 + r * PD + t2 * 16] = (_Float16)(acc[0] + b0);
        }
    }
}

// ---------------------------------------------------------------------------
// 8 -> 27 conv + L1 normalize via MFMA; ROWS=4, LDS-tiled B input.
// Weights direct from global WF (R8 form). WB grouped-planar [7][VOX][4]:
// o0 (taps q*4..q*4+3) -> group q; o1 (taps 16+q*4..) -> group 4+q (q<3).
// Wave stores become 4x128B contiguous runs instead of 56B-stride scatter.
// ---------------------------------------------------------------------------
__global__ __launch_bounds__(256) void conv8x27n_mfma(const _Float16* __restrict__ HP,
                                                      const _Float16* __restrict__ WF,
                                                      _Float16* __restrict__ WB)
{
    __shared__ _Float16 T[3 * 6 * 130 * 8];   // 37,440 B: [dz(3)][yy(6)][xs(130)][ch(8)]
    const int tid = threadIdx.x;

    const int b = ((blockIdx.x & 7) << 9) | (blockIdx.x >> 3);  // 4096 blocks
    const int h0 = (b & 31) << 2;
    const int d  = b >> 5;

    // stage tile: rows (d+dz, h0+yy), yy in [0,6), x in [0,130)
    for (int i = tid; i < 3 * 6 * 130; i += 256) {
        const int dz  = i / 780;
        const int rem = i - dz * 780;
        const int yy  = rem / 130;
        const int xs  = rem - yy * 130;
        ((half8*)T)[i] =
            *(const half8*)&HP[((size_t)((d + dz) * PD + (h0 + yy)) * PD + xs) * 8];
    }

    const int lane = tid & 63;
    const int wv   = tid >> 6;
    const int col  = lane & 15;
    const int q    = lane >> 4;

    // weight fragments straight from global (latency hides under staging)
    half8 af[2][7];
    #pragma unroll
    for (int t = 0; t < 2; ++t)
        #pragma unroll
        for (int c = 0; c < 7; ++c)
            af[t][c] = *(const half8*)&WF[((t * 16 + col) * 29 + (c * 4 + q)) * 8];

    // per-lane LDS base (halves index) for each tap-column c
    int lb[7];
    #pragma unroll
    for (int c = 0; c < 7; ++c) {
        const int tap = min(c * 4 + q, 26);
        const int dz = tap / 9, r9 = tap - dz * 9;
        const int dy = r9 / 3,  dx = r9 - dy * 3;
        lb[c] = ((dz * 6 + dy) * 130 + wv * 32 + col + dx) * 8;
    }

    __syncthreads();

    #pragma unroll
    for (int r = 0; r < 4; ++r) {
        #pragma unroll
        for (int t2 = 0; t2 < 2; ++t2) {
            float4v acc0 = {0.0f, 0.0f, 0.0f, 0.0f};
            float4v acc1 = {0.0f, 0.0f, 0.0f, 0.0f};
            #pragma unroll
            for (int c = 0; c < 7; ++c) {
                const half8 bv = *(const half8*)&T[lb[c] + (r * 130 + t2 * 16) * 8];
                acc0 = __builtin_amdgcn_mfma_f32_16x16x32_f16(af[0][c], bv, acc0, 0, 0, 0);
                acc1 = __builtin_amdgcn_mfma_f32_16x16x32_f16(af[1][c], bv, acc1, 0, 0, 0);
            }

            float s = 0.0f;
            #pragma unroll
            for (int rr = 0; rr < 4; ++rr) {
                s += fabsf(acc0[rr]);
                if (16 + q * 4 + rr < 27) s += fabsf(acc1[rr]);
            }
            s += __shfl_xor(s, 16);
            s += __shfl_xor(s, 32);
            const float rcp = 1.0f / fmaxf(s, 1e-12f);

            const int vox = (d << 14) + ((h0 + r) << 7) + wv * 32 + t2 * 16 + col;
            half4 o0, o1;
            #pragma unroll
            for (int rr = 0; rr < 4; ++rr) {
                o0[rr] = (_Float16)(acc0[rr] * rcp);
                o1[rr] = (_Float16)(acc1[rr] * rcp);   // pad rows produce 0
            }
            *(half4*)&WB[((size_t)q * VOX + vox) * 4] = o0;
            if (q < 3)
                *(half4*)&WB[((size_t)(4 + q) * VOX + vox) * 4] = o1;  // q==3: pad
        }
    }
}

// ---------------------------------------------------------------------------
// Adaptive stencil, 8ch padded interleaved in/out; ROLLING-Z LDS ring,
// 4 y-rows x 128 x per block (512 threads), 8 z-slices per block.
// WB grouped-planar: W[k] load is 512B/wave fully coalesced.
// ---------------------------------------------------------------------------
__global__ __launch_bounds__(512) void aconv8i(const _Float16* __restrict__ in,
                                               const _Float16* __restrict__ wb,
                                               _Float16* __restrict__ out)
{
    __shared__ _Float16 T[4][6 * 130 * 8];   // ring: [slot][(yy*130+xs)*8+ch]
    const int b = ((blockIdx.x & 7) << 6) | (blockIdx.x >> 3);  // 512 blocks
    const int h0 = (b & 31) << 2;
    const int d0 = (b >> 5) << 3;            // chunk of 8 z-slices
    const int tid = threadIdx.x;

    // stage input slice z (unpadded plane index, -1..128) into its ring slot
    auto stage = [&](int z) {
        const int slot = (z + 1) & 3;
        for (int i = tid; i < 6 * 130; i += 512) {
            const int yy = i / 130;
            const int xs = i - yy * 130;
            *(half8*)&T[slot][i * 8] =
                *(const half8*)&in[((size_t)((z + 1) * PD + (h0 + yy)) * PD + xs) * 8];
        }
    };

    stage(d0 - 1); stage(d0); stage(d0 + 1);
    __syncthreads();

    const int x  = tid & 127;
    const int ly = tid >> 7;                  // 0..3: which of the 4 y-rows

    for (int z = d0; z < d0 + 8; ++z) {
        if (z <= d0 + 6) stage(z + 2);        // slot (z+3)&3: holds z-2, not read now

        const int idx = (z << 14) + ((h0 + ly) << 7) + x;
        half4 W[7];
        #pragma unroll
        for (int k = 0; k < 7; ++k)
            W[k] = *(const half4*)(wb + ((size_t)k * VOX + idx) * 4);

        half2v a4[4];
        #pragma unroll
        for (int j = 0; j < 4; ++j) a4[j] = half2v{};

        #pragma unroll
        for (int dz = 0; dz < 3; dz++) {
            const int slot = (z + dz) & 3;    // slice z-1+dz
            #pragma unroll
            for (int dy = 0; dy < 3; dy++) {
                const _Float16* rp = &T[slot][((ly + dy) * 130 + (x + 1)) * 8];
                #pragma unroll
                for (int kw = 0; kw < 3; kw++) {
                    const int tap = dz * 9 + dy * 3 + kw;
                    const _Float16 wt = W[tap >> 2][tap & 3];
                    half2v w2; w2[0] = wt; w2[1] = wt;
                    const half8 hv = *(const half8*)(rp + (kw - 1) * 8);
                    const half2v* h2 = (const half2v*)&hv;
                    #pragma unroll
                    for (int j = 0; j < 4; ++j)
                        a4[j] += h2[j] * w2;             // v_pk_fma_f16
                }
            }
        }

        const int s0 = ((z + 1) * PD + (h0 + ly + 1)) * PD + (x + 1);
        half8 o;
        #pragma unroll
        for (int j = 0; j < 4; ++j) { o[2 * j] = a4[j][0]; o[2 * j + 1] = a4[j][1]; }
        *(half8*)&out[(size_t)s0 * 8] = o;

        __syncthreads();   // reads of slot (z)&3 done before next iter overwrites it
    }
}

// ---------------------------------------------------------------------------
// Adaptive stencil, 1ch padded fp16 in; fp32 math. WB grouped-planar.
// TANH=false: padded fp16 out. TANH=true: planar fp32 out (final).
// ---------------------------------------------------------------------------
template<bool TANH>
__global__ __launch_bounds__(256) void aconv1h(const _Float16* __restrict__ in,
                                               const _Float16* __restrict__ wb,
                                               _Float16* __restrict__ outh,
                                               float* __restrict__ outf)
{
    const int b = ((blockIdx.x & 7) << 10) | (blockIdx.x >> 3);
    const int idx = b * 256 + threadIdx.x;
    const int w = idx & 127;
    const int h = (idx >> 7) & 127;
    const int d = idx >> 14;

    half4 W[7];
    #pragma unroll
    for (int k = 0; k < 7; ++k)
        W[k] = *(const half4*)(wb + ((size_t)k * VOX + idx) * 4);

    const int s0 = ((d + 1) * PD + (h + 1)) * PD + (w + 1);

    float acc = 0.0f;
    #pragma unroll
    for (int dz = 0; dz < 3; dz++) {
        #pragma unroll
        for (int dy = 0; dy < 3; dy++) {
            const _Float16* rp = in + s0 + ((dz - 1) * PD + (dy - 1)) * PD;
            #pragma unroll
            for (int kw = 0; kw < 3; kw++) {
                const int tap = dz * 9 + dy * 3 + kw;
                const _Float16 wt = W[tap >> 2][tap & 3];
                acc = fmaf((float)rp[kw - 1], (float)wt, acc);
            }
        }
    }

    if (TANH) outf[idx] = tanhf(acc);
    else      outh[s0] = (_Float16)acc;
}

// ---------------------------------------------------------------------------
// ws layout (~192 MiB): P0 | P1 (33.5 MiB padded 8-ch each) | WB (112 MiB)
//   | F1 | G1 | F2 (4.2 MiB padded 1-ch each) | WF (preformatted weights).
// WF halves: [0]=ac1_w1 [3712]=ac2_w1 [7424]=ac3_w1 [11136]=out_w
//   [14848]=mid_w [18560]=ac1_w2 [25984]=ac2_w2 [33408]=ac3_w2
// ---------------------------------------------------------------------------
extern "C" void kernel_launch(void* const* d_in, const int* in_sizes, int n_in,
                              void* d_out, int out_size, void* d_ws, size_t ws_size,
                              hipStream_t stream)
{
    const float* x      = (const float*)d_in[0];
    const float* ac1_w1 = (const float*)d_in[1];
    const float* ac1_b1 = (const float*)d_in[2];
    const float* ac1_w2 = (const float*)d_in[3];
    const float* ac2_w1 = (const float*)d_in[4];
    const float* ac2_b1 = (const float*)d_in[5];
    const float* ac2_w2 = (const float*)d_in[6];
    const float* ac3_w1 = (const float*)d_in[7];
    const float* ac3_b1 = (const float*)d_in[8];
    const float* ac3_w2 = (const float*)d_in[9];
    const float* mid_w  = (const float*)d_in[10];
    const float* mid_b  = (const float*)d_in[11];
    const float* out_w  = (const float*)d_in[12];
    const float* out_b  = (const float*)d_in[13];
    float* out = (float*)d_out;

    char* ws = (char*)d_ws;
    const size_t PS8 = (size_t)PD * PD * PD * 8 * 2;   // 35,152,000 B
    const size_t PS1 = (size_t)PD * PD * PD * 2;       //  4,394,000 B
    const size_t WBsz = (size_t)VOX * 28 * 2;          // 117,440,512 B
    _Float16* P0 = (_Float16*)(ws);
    _Float16* P1 = (_Float16*)(ws + PS8);
    _Float16* WB = (_Float16*)(ws + 2 * PS8);
    _Float16* F1 = (_Float16*)(ws + 2 * PS8 + WBsz);
    _Float16* G1 = (_Float16*)(ws + 2 * PS8 + WBsz + PS1);
    _Float16* F2 = (_Float16*)(ws + 2 * PS8 + WBsz + 2 * PS1);
    _Float16* WF = (_Float16*)(ws + 2 * PS8 + WBsz + 3 * PS1);
    _Float16* WF8_1  = WF;
    _Float16* WF8_2  = WF + 3712;
    _Float16* WF8_3  = WF + 7424;
    _Float16* WFo    = WF + 11136;
    _Float16* WFmid  = WF + 14848;
    _Float16* WF27_1 = WF + 18560;
    _Float16* WF27_2 = WF + 25984;
    _Float16* WF27_3 = WF + 33408;

    const dim3 blk(256);
    const dim3 blkA(512);
    const dim3 gridT(VOX / 256);               // cast: 8192 blocks
    const dim3 gridM(VOX / 256);               // ROWS=2 MFMA convs: 8192 blocks
    const dim3 gridM4(VOX / 512);              // conv8x27n (ROWS=4): 4096 blocks
    const dim3 gridA(512);                     // rolling-z aconv8i: 512 blocks
    const dim3 gridZ((PD * PD + 255) / 256);   // zero_halo: 67 blocks

    zero_halo<8><<<gridZ, blk, 0, stream>>>(P0);
    zero_halo<8><<<gridZ, blk, 0, stream>>>(P1);
    zero_halo<1><<<gridZ, blk, 0, stream>>>(F1);
    zero_halo<1><<<gridZ, blk, 0, stream>>>(G1);
    zero_halo<1><<<gridZ, blk, 0, stream>>>(F2);
    preformat<<<dim3(8), blk, 0, stream>>>(ac1_w1, ac2_w1, ac3_w1, out_w, mid_w,
                                           ac1_w2, ac2_w2, ac3_w2, WF);

    // ---- block 1 ----
    cast_hp<<<gridT, blk, 0, stream>>>(x, P0);                       // X16 = P0
    conv8x8_mfma<true ><<<gridM, blk, 0, stream>>>(P0, WF8_1, ac1_b1, P1);   // H1
    conv8x27n_mfma<<<gridM4, blk, 0, stream>>>(P1, WF27_1, WB);
    aconv8i<<<gridA, blkA, 0, stream>>>(P0, WB, P1);                 // (H1 dead)
    aconv8i<<<gridA, blkA, 0, stream>>>(P1, WB, P0);
    aconv8i<<<gridA, blkA, 0, stream>>>(P0, WB, P1);                 // C1 = P1
    // ---- mid conv ----
    conv8x8_mfma<false><<<gridM, blk, 0, stream>>>(P1, WFmid, mid_b, P0);    // M = P0
    // ---- block 2 ----
    conv8x8_mfma<true ><<<gridM, blk, 0, stream>>>(P0, WF8_2, ac2_b1, P1);   // H2
    conv8x27n_mfma<<<gridM4, blk, 0, stream>>>(P1, WF27_2, WB);
    aconv8i<<<gridA, blkA, 0, stream>>>(P0, WB, P1);
    aconv8i<<<gridA, blkA, 0, stream>>>(P1, WB, P0);
    aconv8i<<<gridA, blkA, 0, stream>>>(P0, WB, P1);                 // mid2 = P1
    // ---- block 3 (weights from mid2 = P1) ----
    conv8x8_mfma<true ><<<gridM, blk, 0, stream>>>(P1, WF8_3, ac3_b1, P0);   // H3
    conv8x27n_mfma<<<gridM4, blk, 0, stream>>>(P0, WF27_3, WB);
    conv8x1_mfma<<<gridM, blk, 0, stream>>>(P1, WFo, out_b, F1);
    aconv1h<false><<<gridT, blk, 0, stream>>>(F1, WB, G1, nullptr);
    aconv1h<false><<<gridT, blk, 0, stream>>>(G1, WB, F2, nullptr);
    aconv1h<true ><<<gridT, blk, 0, stream>>>(F2, WB, nullptr, out);
}

// Round 11
// 675.580 us; speedup vs baseline: 1.1394x; 1.0488x over previous
//
#include <hip/hip_runtime.h>
#include <math.h>

#define DSZ 128
#define VOX (DSZ*DSZ*DSZ)  // 2,097,152 voxels
#define PD  130            // padded dim (halo 1 on all 6 faces)

typedef _Float16 half8 __attribute__((ext_vector_type(8)));
typedef _Float16 half4 __attribute__((ext_vector_type(4)));
typedef _Float16 half2v __attribute__((ext_vector_type(2)));
typedef float float4v __attribute__((ext_vector_type(4)));

// Halo-padded tensors: slot(z,y,x) = ((z+1)*130 + (y+1))*130 + (x+1),
// z,y,x in [-1,128]. 8-ch interleaved: halves = slot*8 (33.5 MiB).
// 1-ch: halves = slot (4.2 MiB). Halos zeroed once; interior-only writes.
// WB grouped-planar: [group(7)][vox][4] halves; tap t = (t>>2)*VOX*4 + vox*4
// + (t&3). 117.4 MiB. Group 6 j=3 (tap 27) is pad, never read.

// ---------------------------------------------------------------------------
// Zero the halo of a padded tensor (ws is re-poisoned before every call).
// ---------------------------------------------------------------------------
template<int CH>
__global__ __launch_bounds__(256) void zero_halo(_Float16* __restrict__ P)
{
    const int t = blockIdx.x * 256 + threadIdx.x;   // (zp,yp) row in [0,130)^2
    if (t >= PD * PD) return;
    const int zp = t / PD;
    const int yp = t - zp * PD;
    _Float16* row = P + (size_t)t * PD * CH;
    if (zp == 0 || zp == PD - 1 || yp == 0 || yp == PD - 1) {
        if (CH == 8) {
            half8 zz = {};
            for (int x = 0; x < PD; ++x) *(half8*)&row[x * 8] = zz;
        } else {
            for (int x = 0; x < PD; ++x) row[x] = (_Float16)0.0f;
        }
    } else {
        if (CH == 8) {
            half8 zz = {};
            *(half8*)&row[0] = zz;
            *(half8*)&row[(PD - 1) * 8] = zz;
        } else {
            row[0] = (_Float16)0.0f;
            row[PD - 1] = (_Float16)0.0f;
        }
    }
}

// ---------------------------------------------------------------------------
// Preformat conv weights -> fp16 [oc][tap(stride 29)][ic], once per launch.
// Blocks: 0..2 = ac{1,2,3}_w1; 3 = out_w; 4 = mid_w; 5..7 = ac{1,2,3}_w2.
// ---------------------------------------------------------------------------
__global__ __launch_bounds__(256) void preformat(const float* __restrict__ w1a, const float* __restrict__ w1b,
                                                 const float* __restrict__ w1c, const float* __restrict__ outw,
                                                 const float* __restrict__ midw,
                                                 const float* __restrict__ w2a, const float* __restrict__ w2b,
                                                 const float* __restrict__ w2c, _Float16* __restrict__ WF)
{
    const int bid = blockIdx.x, tid = threadIdx.x;
    const float* src;
    _Float16* dst;
    int nelem, sz;
    if (bid < 3)       { src = bid == 0 ? w1a : bid == 1 ? w1b : w1c; dst = WF + bid * 3712; nelem = 8 * 216; sz = 16 * 29; }
    else if (bid == 3) { src = outw; dst = WF + 3 * 3712; nelem = 216;     sz = 16 * 29; }
    else if (bid == 4) { src = midw; dst = WF + 4 * 3712; nelem = 8 * 216; sz = 16 * 29; }
    else               { src = bid == 5 ? w2a : bid == 6 ? w2b : w2c; dst = WF + 5 * 3712 + (bid - 5) * 7424; nelem = 27 * 216; sz = 32 * 29; }
    for (int i = tid; i < sz; i += 256) ((half8*)dst)[i] = half8{};
    __syncthreads();
    for (int i = tid; i < nelem; i += 256) {
        const int oc = i / 216;
        const int rem = i - oc * 216;
        const int ic = rem / 27;
        const int tap = rem - ic * 27;
        dst[(oc * 29 + tap) * 8 + ic] = (_Float16)src[i];
    }
}

// ---------------------------------------------------------------------------
// Cast planar fp32 (8ch) -> halo-padded interleaved fp16 (interior only).
// ---------------------------------------------------------------------------
__global__ __launch_bounds__(256) void cast_hp(const float* __restrict__ in,
                                               _Float16* __restrict__ hp)
{
    const int idx = blockIdx.x * 256 + threadIdx.x;
    const int w = idx & 127;
    const int h = (idx >> 7) & 127;
    const int d = idx >> 14;
    half8 v;
    #pragma unroll
    for (int ic = 0; ic < 8; ++ic) v[ic] = (_Float16)in[(size_t)ic * VOX + idx];
    const int slot = ((d + 1) * PD + (h + 1)) * PD + (w + 1);
    *(half8*)&hp[(size_t)slot * 8] = v;
}

// ---------------------------------------------------------------------------
// Dense 3x3x3 conv 8->8 (+bias, opt relu) via MFMA; ROWS=4, LDS-tiled B
// input, weights direct from global WF (R5+R8-verified conv8x27n recipe).
// ---------------------------------------------------------------------------
template<bool RELU>
__global__ __launch_bounds__(256) void conv8x8_mfma(const _Float16* __restrict__ DP,
                                                    const _Float16* __restrict__ WF,
                                                    const float* __restrict__ bias,
                                                    _Float16* __restrict__ HO)
{
    __shared__ _Float16 T[3 * 6 * 130 * 8];   // 37,440 B
    const int tid = threadIdx.x;

    const int b = ((blockIdx.x & 7) << 9) | (blockIdx.x >> 3);  // 4096 blocks
    const int h0 = (b & 31) << 2;
    const int d  = b >> 5;

    for (int i = tid; i < 3 * 6 * 130; i += 256) {
        const int dz  = i / 780;
        const int rem = i - dz * 780;
        const int yy  = rem / 130;
        const int xs  = rem - yy * 130;
        ((half8*)T)[i] =
            *(const half8*)&DP[((size_t)((d + dz) * PD + (h0 + yy)) * PD + xs) * 8];
    }

    const int lane = tid & 63;
    const int wv   = tid >> 6;
    const int col  = lane & 15;
    const int q    = lane >> 4;

    // weight fragments straight from global (oc>=8 slots are zeroed)
    half8 af[7];
    #pragma unroll
    for (int c = 0; c < 7; ++c)
        af[c] = *(const half8*)&WF[(col * 29 + (c * 4 + q)) * 8];

    int lb[7];
    #pragma unroll
    for (int c = 0; c < 7; ++c) {
        const int tap = min(c * 4 + q, 26);
        const int dz = tap / 9, r9 = tap - dz * 9;
        const int dy = r9 / 3,  dx = r9 - dy * 3;
        lb[c] = ((dz * 6 + dy) * 130 + wv * 32 + col + dx) * 8;
    }

    __syncthreads();

    const int base0 = ((d + 1) * PD + (h0 + 1)) * PD + 1 + wv * 32 + col;

    #pragma unroll
    for (int r = 0; r < 4; ++r) {
        #pragma unroll
        for (int t2 = 0; t2 < 2; ++t2) {
            float4v acc = {0.0f, 0.0f, 0.0f, 0.0f};
            #pragma unroll
            for (int c = 0; c < 7; ++c) {
                const half8 bv = *(const half8*)&T[lb[c] + (r * 130 + t2 * 16) * 8];
                acc = __builtin_amdgcn_mfma_f32_16x16x32_f16(af[c], bv, acc, 0, 0, 0);
            }
            if (q < 2) {
                const float4v bl = ((const float4v*)bias)[q];
                half4 hv;
                #pragma unroll
                for (int rr = 0; rr < 4; ++rr) {
                    float v = acc[rr] + bl[rr];
                    if (RELU) v = fmaxf(v, 0.0f);
                    hv[rr] = (_Float16)v;
                }
                *(half4*)&HO[(size_t)(base0 + r * PD + t2 * 16) * 8 + q * 4] = hv;
            }
        }
    }
}

// ---------------------------------------------------------------------------
// Dense 3x3x3 conv 8->1 (+bias) via MFMA; ROWS=4, LDS-tiled B input,
// weights direct from global (same recipe). Padded 1-ch fp16 out.
// ---------------------------------------------------------------------------
__global__ __launch_bounds__(256) void conv8x1_mfma(const _Float16* __restrict__ DP,
                                                    const _Float16* __restrict__ WF,
                                                    const float* __restrict__ bias,
                                                    _Float16* __restrict__ F)
{
    __shared__ _Float16 T[3 * 6 * 130 * 8];   // 37,440 B
    const int tid = threadIdx.x;

    const int b = ((blockIdx.x & 7) << 9) | (blockIdx.x >> 3);  // 4096 blocks
    const int h0 = (b & 31) << 2;
    const int d  = b >> 5;

    for (int i = tid; i < 3 * 6 * 130; i += 256) {
        const int dz  = i / 780;
        const int rem = i - dz * 780;
        const int yy  = rem / 130;
        const int xs  = rem - yy * 130;
        ((half8*)T)[i] =
            *(const half8*)&DP[((size_t)((d + dz) * PD + (h0 + yy)) * PD + xs) * 8];
    }

    const int lane = tid & 63;
    const int wv   = tid >> 6;
    const int col  = lane & 15;
    const int q    = lane >> 4;

    half8 af[7];
    #pragma unroll
    for (int c = 0; c < 7; ++c)
        af[c] = *(const half8*)&WF[(col * 29 + (c * 4 + q)) * 8];

    int lb[7];
    #pragma unroll
    for (int c = 0; c < 7; ++c) {
        const int tap = min(c * 4 + q, 26);
        const int dz = tap / 9, r9 = tap - dz * 9;
        const int dy = r9 / 3,  dx = r9 - dy * 3;
        lb[c] = ((dz * 6 + dy) * 130 + wv * 32 + col + dx) * 8;
    }

    __syncthreads();

    const int base0 = ((d + 1) * PD + (h0 + 1)) * PD + 1 + wv * 32 + col;
    const float b0 = bias[0];

    #pragma unroll
    for (int r = 0; r < 4; ++r) {
        #pragma unroll
        for (int t2 = 0; t2 < 2; ++t2) {
            float4v acc = {0.0f, 0.0f, 0.0f, 0.0f};
            #pragma unroll
            for (int c = 0; c < 7; ++c) {
                const half8 bv = *(const half8*)&T[lb[c] + (r * 130 + t2 * 16) * 8];
                acc = __builtin_amdgcn_mfma_f32_16x16x32_f16(af[c], bv, acc, 0, 0, 0);
            }
            if (q == 0)
                F[base0 + r * PD + t2 * 16] = (_Float16)(acc[0] + b0);
        }
    }
}

// ---------------------------------------------------------------------------
// 8 -> 27 conv + L1 normalize via MFMA; ROWS=4, LDS-tiled B input.
// Weights direct from global WF. WB grouped-planar [7][VOX][4].
// (R8/R9-verified form.)
// ---------------------------------------------------------------------------
__global__ __launch_bounds__(256) void conv8x27n_mfma(const _Float16* __restrict__ HP,
                                                      const _Float16* __restrict__ WF,
                                                      _Float16* __restrict__ WB)
{
    __shared__ _Float16 T[3 * 6 * 130 * 8];   // 37,440 B: [dz(3)][yy(6)][xs(130)][ch(8)]
    const int tid = threadIdx.x;

    const int b = ((blockIdx.x & 7) << 9) | (blockIdx.x >> 3);  // 4096 blocks
    const int h0 = (b & 31) << 2;
    const int d  = b >> 5;

    // stage tile: rows (d+dz, h0+yy), yy in [0,6), x in [0,130)
    for (int i = tid; i < 3 * 6 * 130; i += 256) {
        const int dz  = i / 780;
        const int rem = i - dz * 780;
        const int yy  = rem / 130;
        const int xs  = rem - yy * 130;
        ((half8*)T)[i] =
            *(const half8*)&HP[((size_t)((d + dz) * PD + (h0 + yy)) * PD + xs) * 8];
    }

    const int lane = tid & 63;
    const int wv   = tid >> 6;
    const int col  = lane & 15;
    const int q    = lane >> 4;

    // weight fragments straight from global (latency hides under staging)
    half8 af[2][7];
    #pragma unroll
    for (int t = 0; t < 2; ++t)
        #pragma unroll
        for (int c = 0; c < 7; ++c)
            af[t][c] = *(const half8*)&WF[((t * 16 + col) * 29 + (c * 4 + q)) * 8];

    // per-lane LDS base (halves index) for each tap-column c
    int lb[7];
    #pragma unroll
    for (int c = 0; c < 7; ++c) {
        const int tap = min(c * 4 + q, 26);
        const int dz = tap / 9, r9 = tap - dz * 9;
        const int dy = r9 / 3,  dx = r9 - dy * 3;
        lb[c] = ((dz * 6 + dy) * 130 + wv * 32 + col + dx) * 8;
    }

    __syncthreads();

    #pragma unroll
    for (int r = 0; r < 4; ++r) {
        #pragma unroll
        for (int t2 = 0; t2 < 2; ++t2) {
            float4v acc0 = {0.0f, 0.0f, 0.0f, 0.0f};
            float4v acc1 = {0.0f, 0.0f, 0.0f, 0.0f};
            #pragma unroll
            for (int c = 0; c < 7; ++c) {
                const half8 bv = *(const half8*)&T[lb[c] + (r * 130 + t2 * 16) * 8];
                acc0 = __builtin_amdgcn_mfma_f32_16x16x32_f16(af[0][c], bv, acc0, 0, 0, 0);
                acc1 = __builtin_amdgcn_mfma_f32_16x16x32_f16(af[1][c], bv, acc1, 0, 0, 0);
            }

            float s = 0.0f;
            #pragma unroll
            for (int rr = 0; rr < 4; ++rr) {
                s += fabsf(acc0[rr]);
                if (16 + q * 4 + rr < 27) s += fabsf(acc1[rr]);
            }
            s += __shfl_xor(s, 16);
            s += __shfl_xor(s, 32);
            const float rcp = 1.0f / fmaxf(s, 1e-12f);

            const int vox = (d << 14) + ((h0 + r) << 7) + wv * 32 + t2 * 16 + col;
            half4 o0, o1;
            #pragma unroll
            for (int rr = 0; rr < 4; ++rr) {
                o0[rr] = (_Float16)(acc0[rr] * rcp);
                o1[rr] = (_Float16)(acc1[rr] * rcp);   // pad rows produce 0
            }
            *(half4*)&WB[((size_t)q * VOX + vox) * 4] = o0;
            if (q < 3)
                *(half4*)&WB[((size_t)(4 + q) * VOX + vox) * 4] = o1;  // q==3: pad
        }
    }
}

// ---------------------------------------------------------------------------
// Adaptive stencil, 8ch padded interleaved in/out; ROLLING-Z LDS ring,
// 4 y-rows x 128 x per block (512 threads), 8 z-slices per block.
// WB grouped-planar: W[k] load is 512B/wave fully coalesced.
// ---------------------------------------------------------------------------
__global__ __launch_bounds__(512) void aconv8i(const _Float16* __restrict__ in,
                                               const _Float16* __restrict__ wb,
                                               _Float16* __restrict__ out)
{
    __shared__ _Float16 T[4][6 * 130 * 8];   // ring: [slot][(yy*130+xs)*8+ch]
    const int b = ((blockIdx.x & 7) << 6) | (blockIdx.x >> 3);  // 512 blocks
    const int h0 = (b & 31) << 2;
    const int d0 = (b >> 5) << 3;            // chunk of 8 z-slices
    const int tid = threadIdx.x;

    // stage input slice z (unpadded plane index, -1..128) into its ring slot
    auto stage = [&](int z) {
        const int slot = (z + 1) & 3;
        for (int i = tid; i < 6 * 130; i += 512) {
            const int yy = i / 130;
            const int xs = i - yy * 130;
            *(half8*)&T[slot][i * 8] =
                *(const half8*)&in[((size_t)((z + 1) * PD + (h0 + yy)) * PD + xs) * 8];
        }
    };

    stage(d0 - 1); stage(d0); stage(d0 + 1);
    __syncthreads();

    const int x  = tid & 127;
    const int ly = tid >> 7;                  // 0..3: which of the 4 y-rows

    for (int z = d0; z < d0 + 8; ++z) {
        if (z <= d0 + 6) stage(z + 2);        // slot (z+3)&3: holds z-2, not read now

        const int idx = (z << 14) + ((h0 + ly) << 7) + x;
        half4 W[7];
        #pragma unroll
        for (int k = 0; k < 7; ++k)
            W[k] = *(const half4*)(wb + ((size_t)k * VOX + idx) * 4);

        half2v a4[4];
        #pragma unroll
        for (int j = 0; j < 4; ++j) a4[j] = half2v{};

        #pragma unroll
        for (int dz = 0; dz < 3; dz++) {
            const int slot = (z + dz) & 3;    // slice z-1+dz
            #pragma unroll
            for (int dy = 0; dy < 3; dy++) {
                const _Float16* rp = &T[slot][((ly + dy) * 130 + (x + 1)) * 8];
                #pragma unroll
                for (int kw = 0; kw < 3; kw++) {
                    const int tap = dz * 9 + dy * 3 + kw;
                    const _Float16 wt = W[tap >> 2][tap & 3];
                    half2v w2; w2[0] = wt; w2[1] = wt;
                    const half8 hv = *(const half8*)(rp + (kw - 1) * 8);
                    const half2v* h2 = (const half2v*)&hv;
                    #pragma unroll
                    for (int j = 0; j < 4; ++j)
                        a4[j] += h2[j] * w2;             // v_pk_fma_f16
                }
            }
        }

        const int s0 = ((z + 1) * PD + (h0 + ly + 1)) * PD + (x + 1);
        half8 o;
        #pragma unroll
        for (int j = 0; j < 4; ++j) { o[2 * j] = a4[j][0]; o[2 * j + 1] = a4[j][1]; }
        *(half8*)&out[(size_t)s0 * 8] = o;

        __syncthreads();   // reads of slot (z)&3 done before next iter overwrites it
    }
}

// ---------------------------------------------------------------------------
// Adaptive stencil, 1ch padded fp16 in; fp32 math. WB grouped-planar.
// TANH=false: padded fp16 out. TANH=true: planar fp32 out (final).
// ---------------------------------------------------------------------------
template<bool TANH>
__global__ __launch_bounds__(256) void aconv1h(const _Float16* __restrict__ in,
                                               const _Float16* __restrict__ wb,
                                               _Float16* __restrict__ outh,
                                               float* __restrict__ outf)
{
    const int b = ((blockIdx.x & 7) << 10) | (blockIdx.x >> 3);
    const int idx = b * 256 + threadIdx.x;
    const int w = idx & 127;
    const int h = (idx >> 7) & 127;
    const int d = idx >> 14;

    half4 W[7];
    #pragma unroll
    for (int k = 0; k < 7; ++k)
        W[k] = *(const half4*)(wb + ((size_t)k * VOX + idx) * 4);

    const int s0 = ((d + 1) * PD + (h + 1)) * PD + (w + 1);

    float acc = 0.0f;
    #pragma unroll
    for (int dz = 0; dz < 3; dz++) {
        #pragma unroll
        for (int dy = 0; dy < 3; dy++) {
            const _Float16* rp = in + s0 + ((dz - 1) * PD + (dy - 1)) * PD;
            #pragma unroll
            for (int kw = 0; kw < 3; kw++) {
                const int tap = dz * 9 + dy * 3 + kw;
                const _Float16 wt = W[tap >> 2][tap & 3];
                acc = fmaf((float)rp[kw - 1], (float)wt, acc);
            }
        }
    }

    if (TANH) outf[idx] = tanhf(acc);
    else      outh[s0] = (_Float16)acc;
}

// ---------------------------------------------------------------------------
// ws layout (~192 MiB): P0 | P1 (33.5 MiB padded 8-ch each) | WB (112 MiB)
//   | F1 | G1 | F2 (4.2 MiB padded 1-ch each) | WF (preformatted weights).
// WF halves: [0]=ac1_w1 [3712]=ac2_w1 [7424]=ac3_w1 [11136]=out_w
//   [14848]=mid_w [18560]=ac1_w2 [25984]=ac2_w2 [33408]=ac3_w2
// ---------------------------------------------------------------------------
extern "C" void kernel_launch(void* const* d_in, const int* in_sizes, int n_in,
                              void* d_out, int out_size, void* d_ws, size_t ws_size,
                              hipStream_t stream)
{
    const float* x      = (const float*)d_in[0];
    const float* ac1_w1 = (const float*)d_in[1];
    const float* ac1_b1 = (const float*)d_in[2];
    const float* ac1_w2 = (const float*)d_in[3];
    const float* ac2_w1 = (const float*)d_in[4];
    const float* ac2_b1 = (const float*)d_in[5];
    const float* ac2_w2 = (const float*)d_in[6];
    const float* ac3_w1 = (const float*)d_in[7];
    const float* ac3_b1 = (const float*)d_in[8];
    const float* ac3_w2 = (const float*)d_in[9];
    const float* mid_w  = (const float*)d_in[10];
    const float* mid_b  = (const float*)d_in[11];
    const float* out_w  = (const float*)d_in[12];
    const float* out_b  = (const float*)d_in[13];
    float* out = (float*)d_out;

    char* ws = (char*)d_ws;
    const size_t PS8 = (size_t)PD * PD * PD * 8 * 2;   // 35,152,000 B
    const size_t PS1 = (size_t)PD * PD * PD * 2;       //  4,394,000 B
    const size_t WBsz = (size_t)VOX * 28 * 2;          // 117,440,512 B
    _Float16* P0 = (_Float16*)(ws);
    _Float16* P1 = (_Float16*)(ws + PS8);
    _Float16* WB = (_Float16*)(ws + 2 * PS8);
    _Float16* F1 = (_Float16*)(ws + 2 * PS8 + WBsz);
    _Float16* G1 = (_Float16*)(ws + 2 * PS8 + WBsz + PS1);
    _Float16* F2 = (_Float16*)(ws + 2 * PS8 + WBsz + 2 * PS1);
    _Float16* WF = (_Float16*)(ws + 2 * PS8 + WBsz + 3 * PS1);
    _Float16* WF8_1  = WF;
    _Float16* WF8_2  = WF + 3712;
    _Float16* WF8_3  = WF + 7424;
    _Float16* WFo    = WF + 11136;
    _Float16* WFmid  = WF + 14848;
    _Float16* WF27_1 = WF + 18560;
    _Float16* WF27_2 = WF + 25984;
    _Float16* WF27_3 = WF + 33408;

    const dim3 blk(256);
    const dim3 blkA(512);
    const dim3 gridT(VOX / 256);               // cast: 8192 blocks
    const dim3 gridM4(VOX / 512);              // ROWS=4 MFMA convs: 4096 blocks
    const dim3 gridA(512);                     // rolling-z aconv8i: 512 blocks
    const dim3 gridZ((PD * PD + 255) / 256);   // zero_halo: 67 blocks

    zero_halo<8><<<gridZ, blk, 0, stream>>>(P0);
    zero_halo<8><<<gridZ, blk, 0, stream>>>(P1);
    zero_halo<1><<<gridZ, blk, 0, stream>>>(F1);
    zero_halo<1><<<gridZ, blk, 0, stream>>>(G1);
    zero_halo<1><<<gridZ, blk, 0, stream>>>(F2);
    preformat<<<dim3(8), blk, 0, stream>>>(ac1_w1, ac2_w1, ac3_w1, out_w, mid_w,
                                           ac1_w2, ac2_w2, ac3_w2, WF);

    // ---- block 1 ----
    cast_hp<<<gridT, blk, 0, stream>>>(x, P0);                       // X16 = P0
    conv8x8_mfma<true ><<<gridM4, blk, 0, stream>>>(P0, WF8_1, ac1_b1, P1);  // H1
    conv8x27n_mfma<<<gridM4, blk, 0, stream>>>(P1, WF27_1, WB);
    aconv8i<<<gridA, blkA, 0, stream>>>(P0, WB, P1);                 // (H1 dead)
    aconv8i<<<gridA, blkA, 0, stream>>>(P1, WB, P0);
    aconv8i<<<gridA, blkA, 0, stream>>>(P0, WB, P1);                 // C1 = P1
    // ---- mid conv ----
    conv8x8_mfma<false><<<gridM4, blk, 0, stream>>>(P1, WFmid, mid_b, P0);   // M = P0
    // ---- block 2 ----
    conv8x8_mfma<true ><<<gridM4, blk, 0, stream>>>(P0, WF8_2, ac2_b1, P1);  // H2
    conv8x27n_mfma<<<gridM4, blk, 0, stream>>>(P1, WF27_2, WB);
    aconv8i<<<gridA, blkA, 0, stream>>>(P0, WB, P1);
    aconv8i<<<gridA, blkA, 0, stream>>>(P1, WB, P0);
    aconv8i<<<gridA, blkA, 0, stream>>>(P0, WB, P1);                 // mid2 = P1
    // ---- block 3 (weights from mid2 = P1) ----
    conv8x8_mfma<true ><<<gridM4, blk, 0, stream>>>(P1, WF8_3, ac3_b1, P0);  // H3
    conv8x27n_mfma<<<gridM4, blk, 0, stream>>>(P0, WF27_3, WB);
    conv8x1_mfma<<<gridM4, blk, 0, stream>>>(P1, WFo, out_b, F1);
    aconv1h<false><<<gridT, blk, 0, stream>>>(F1, WB, G1, nullptr);
    aconv1h<false><<<gridT, blk, 0, stream>>>(G1, WB, F2, nullptr);
    aconv1h<true ><<<gridT, blk, 0, stream>>>(F2, WB, nullptr, out);
}